// Round 5
// baseline (7822.346 us; speedup 1.0000x reference)
//
#include <hip/hip_runtime.h>
#include <math.h>

// Problem constants
#define NCOMP 20000
#define SEQT  32
#define INSZ  64
#define HSZ   128
#define EINTRA 640000
#define EINTER 4096
#define NSEC  64

#define LDH 132   // padded LDS row stride (floats) for gat_transform

typedef __attribute__((ext_vector_type(8))) short bf16x8;   // 8 bf16 in 4 VGPRs
typedef __attribute__((ext_vector_type(4))) float f32x4;    // MFMA C/D frag

__device__ __forceinline__ float dot4f(float4 a, float4 b){
  return a.x*b.x + a.y*b.y + a.z*b.z + a.w*b.w;
}
__device__ __forceinline__ float sigm(float x){ return 1.f/(1.f + __expf(-x)); }
__device__ __forceinline__ float ftanh(float x){
  float cx = fminf(fmaxf(x, -15.f), 15.f);
  float e = __expf(2.f*cx);
  return (e - 1.f)/(e + 1.f);
}
// monotone float<->uint mapping so atomicMax works for signed floats (inter path)
__device__ __forceinline__ unsigned fordu(float f){
  unsigned b = __float_as_uint(f);
  return (b & 0x80000000u) ? ~b : (b | 0x80000000u);
}
__device__ __forceinline__ float unfordu(unsigned u){
  unsigned b = (u & 0x80000000u) ? (u & 0x7fffffffu) : ~u;
  return __uint_as_float(b);
}
#define NEG_MAX_ORD 0x00800000u   // fordu(-FLT_MAX)

// bf16 hi/lo split helpers (truncation split: w = hi + rem exactly, lo = bf16(rem))
__device__ __forceinline__ unsigned short bf16hi(float f){
  return (unsigned short)(__float_as_uint(f) >> 16);
}
__device__ __forceinline__ float bf16tof(unsigned short h){
  return __uint_as_float(((unsigned)h) << 16);
}

// ===========================================================================
// Weight packing for MFMA bf16x3: out[(kt*24+nt)*2+{hi,lo}][lane][8 bf16].
// Fragment convention (must match A-side): col n = lane&15 (within nt tile),
// k = kt*32 + (lane>>4)*8 + j.  One coalesced dwordx4 per fragment at use.
// ===========================================================================
__global__ void wpack_mfma(const float* __restrict__ W, unsigned short* __restrict__ out, int K)
{
  int tid = blockIdx.x*256 + threadIdx.x;
  int KT = K >> 5;
  if (tid >= KT*24*64) return;
  int lane = tid & 63;
  int nt   = (tid >> 6) % 24;
  int kt   = (tid >> 6) / 24;
  int col  = nt*16 + (lane & 15);
  int kbase = kt*32 + (lane >> 4)*8;
  size_t b = ((size_t)(kt*24 + nt)*2*64 + lane)*8;   // hi at b, lo at b+512
  #pragma unroll
  for (int j = 0; j < 8; ++j){
    float w = W[(size_t)col*K + kbase + j];
    unsigned short h = bf16hi(w);
    float rem = w - bf16tof(h);
    out[b + j]       = h;
    out[b + 512 + j] = bf16hi(rem);
  }
}

// ===========================================================================
// MFMA bf16x3 fused 2-layer GRU.
// Block = 128 thr (2 waves) = 16 companies (one 16x16x32 M-tile), 1250 blocks.
// Wave w owns N-tiles {w*4..w*4+3} of each gate (dims [64w, 64w+64)) -> the
// GRU elementwise is fully wave-local; h (bf16 hi+lo, [dim][comp]) is shared
// LDS, so 4 barriers/t order the cross-wave h read/write phases.
// Each product GEMM runs 3 MFMA passes (AhBh + AhBl + AlBh) into one fp32
// C-frag => ~2^-16 relative input error (fp32-emulation, "bf16x3").
// C/D layout (m89-verified): col=lane&15, row=(lane>>4)*4+reg.
// A/B k-slots use the SAME bijection -> contraction correct for any HW k-map.
// ===========================================================================
__global__ __launch_bounds__(128, 2)
void gru_mfma(const float* __restrict__ x,
              const unsigned short* __restrict__ w0pk, const unsigned short* __restrict__ u0pk,
              const unsigned short* __restrict__ w1pk, const unsigned short* __restrict__ u1pk,
              const float* __restrict__ bih0, const float* __restrict__ bhh0,
              const float* __restrict__ bih1, const float* __restrict__ bhh1,
              float* __restrict__ seq)
{
  __shared__ __align__(16) unsigned short hs[4][2048];  // h0hi,h0lo,h1hi,h1lo : [dim*16+comp]
  __shared__ float bias[1024];  // [0:128)R0 [128:256)Z0 [256:384)NX0 [384:512)NH0, +512 layer1

  const int tid  = threadIdx.x;
  const int wave = tid >> 6, l = tid & 63;
  const int cq = l & 15, kg = l >> 4;
  const int sbase = wave*4;                 // this wave's N-tile base (per gate)
  const int cbase = blockIdx.x*16;          // 1250*16 == 20000 exactly, no tail

  // stage biases (merged R/Z, split NX/NH) + zero h state; one barrier
  for (int i = tid; i < 1024; i += 128){
    float v;
    if      (i <  256) v = bih0[i] + bhh0[i];
    else if (i <  384) v = bih0[i];             // 256+(i-256)
    else if (i <  512) v = bhh0[i - 128];       // 256+(i-384)
    else if (i <  768) v = bih1[i - 512] + bhh1[i - 512];
    else if (i <  896) v = bih1[i - 512];       // 256+(i-768)
    else               v = bhh1[i - 640];       // 256+(i-896)
    bias[i] = v;
  }
  {
    float4 z4 = make_float4(0.f,0.f,0.f,0.f);
    float4* hz = (float4*)&hs[0][0];
    for (int i = tid; i < 1024; i += 128) hz[i] = z4;   // 16 KB
  }
  __syncthreads();

  unsigned short* h0hi = hs[0];
  unsigned short* h0lo = hs[1];
  unsigned short* h1hi = hs[2];
  unsigned short* h1lo = hs[3];

  // ---- macros (kept as macros so all C-frag indexing stays static => regs) ----
  #define CINIT(BOFS) do { \
    _Pragma("unroll") for (int s = 0; s < 4; ++s){ \
      float b0 = bias[(BOFS)       + (sbase+s)*16 + cq]; \
      float b1 = bias[(BOFS) + 128 + (sbase+s)*16 + cq]; \
      float b2 = bias[(BOFS) + 256 + (sbase+s)*16 + cq]; \
      float b3 = bias[(BOFS) + 384 + (sbase+s)*16 + cq]; \
      crz[s]   = (f32x4){b0,b0,b0,b0}; \
      crz[4+s] = (f32x4){b1,b1,b1,b1}; \
      cnx[s]   = (f32x4){b2,b2,b2,b2}; \
      cnh[s]   = (f32x4){b3,b3,b3,b3}; } \
  } while(0)

  #define LOADA(HI, LO, KT, AH, AL) do { \
    int _kb = ((KT)*32 + kg*8)*16 + cq; \
    _Pragma("unroll") for (int j = 0; j < 8; ++j){ \
      AH[j] = (short)(HI)[_kb + j*16]; \
      AL[j] = (short)(LO)[_kb + j*16]; } \
  } while(0)

  #define MF3(AH, AL, BH, BL, C) do { \
    C = __builtin_amdgcn_mfma_f32_16x16x32_bf16(AH, BH, C, 0,0,0); \
    C = __builtin_amdgcn_mfma_f32_16x16x32_bf16(AH, BL, C, 0,0,0); \
    C = __builtin_amdgcn_mfma_f32_16x16x32_bf16(AL, BH, C, 0,0,0); \
  } while(0)

  #define GEMM12(PK, KT, AH, AL, CN) do { \
    const unsigned short* _p = (PK) + (size_t)(KT)*24*1024 + (size_t)l*8; \
    _Pragma("unroll") for (int s = 0; s < 4; ++s){ \
      { const bf16x8* bp = (const bf16x8*)(_p + (size_t)(sbase+s)*1024); \
        bf16x8 bh = bp[0], bl = bp[64]; MF3(AH, AL, bh, bl, crz[s]); } \
      { const bf16x8* bp = (const bf16x8*)(_p + (size_t)(8 + sbase+s)*1024); \
        bf16x8 bh = bp[0], bl = bp[64]; MF3(AH, AL, bh, bl, crz[4+s]); } \
      { const bf16x8* bp = (const bf16x8*)(_p + (size_t)(16 + sbase+s)*1024); \
        bf16x8 bh = bp[0], bl = bp[64]; MF3(AH, AL, bh, bl, CN[s]); } } \
  } while(0)

  #define ELEM(HHI, HLO, DOSTORE) do { \
    _Pragma("unroll") for (int s = 0; s < 4; ++s){ \
      int d  = (sbase+s)*16 + cq; \
      int eb = d*16 + kg*4; \
      ushort4 oh = *(const ushort4*)&(HHI)[eb]; \
      ushort4 ol = *(const ushort4*)&(HLO)[eb]; \
      float hold[4] = { bf16tof(oh.x)+bf16tof(ol.x), bf16tof(oh.y)+bf16tof(ol.y), \
                        bf16tof(oh.z)+bf16tof(ol.z), bf16tof(oh.w)+bf16tof(ol.w) }; \
      unsigned short nh_[4], nl_[4]; float hnv[4]; \
      _Pragma("unroll") for (int r = 0; r < 4; ++r){ \
        float rr = sigm(crz[s][r]); \
        float zz = sigm(crz[4+s][r]); \
        float nn = ftanh(cnx[s][r] + rr*cnh[s][r]); \
        float hn = (1.f - zz)*nn + zz*hold[r]; \
        unsigned short hh = bf16hi(hn); \
        nh_[r] = hh; nl_[r] = bf16hi(hn - bf16tof(hh)); hnv[r] = hn; } \
      *(ushort4*)&(HHI)[eb] = make_ushort4(nh_[0], nh_[1], nh_[2], nh_[3]); \
      *(ushort4*)&(HLO)[eb] = make_ushort4(nl_[0], nl_[1], nl_[2], nl_[3]); \
      if (DOSTORE){ \
        _Pragma("unroll") for (int r = 0; r < 4; ++r) \
          seq[(size_t)(cbase + kg*4 + r)*HSZ + d] = hnv[r]; } } \
  } while(0)

  #pragma unroll 1
  for (int t = 0; t < SEQT; ++t){
    f32x4 crz[8], cnx[4], cnh[4];
    // ================= layer 0 =================
    CINIT(0);
    for (int kt = 0; kt < 2; ++kt){           // x part, K=64 (A direct from global)
      const float* xp = x + ((size_t)(cbase + cq)*SEQT + t)*INSZ + kt*32 + kg*8;
      float4 q0 = *(const float4*)xp;
      float4 q1 = *(const float4*)(xp + 4);
      float xf[8] = {q0.x,q0.y,q0.z,q0.w, q1.x,q1.y,q1.z,q1.w};
      bf16x8 ah, al;
      #pragma unroll
      for (int j = 0; j < 8; ++j){
        unsigned short h = bf16hi(xf[j]);
        ah[j] = (short)h;
        al[j] = (short)bf16hi(xf[j] - bf16tof(h));
      }
      GEMM12(w0pk, kt, ah, al, cnx);
    }
    for (int kt = 0; kt < 4; ++kt){           // h part, K=128 (A from LDS h0)
      bf16x8 ah, al; LOADA(h0hi, h0lo, kt, ah, al);
      GEMM12(u0pk, kt, ah, al, cnh);
    }
    __syncthreads();                           // all waves done reading h0_old
    ELEM(h0hi, h0lo, false);
    __syncthreads();                           // h0_new visible
    // ================= layer 1 =================
    CINIT(512);
    for (int kt = 0; kt < 4; ++kt){           // input = h0_new
      bf16x8 ah, al; LOADA(h0hi, h0lo, kt, ah, al);
      GEMM12(w1pk, kt, ah, al, cnx);
    }
    for (int kt = 0; kt < 4; ++kt){           // hidden h1_old
      bf16x8 ah, al; LOADA(h1hi, h1lo, kt, ah, al);
      GEMM12(u1pk, kt, ah, al, cnh);
    }
    __syncthreads();                           // all waves done reading h1_old
    ELEM(h1hi, h1lo, (t == SEQT-1));
    __syncthreads();                           // h1_new visible for next t
  }
  #undef CINIT
  #undef LOADA
  #undef MF3
  #undef GEMM12
  #undef ELEM
}

// ===========================================================================
// GAT stage — CSR build + atomic-free per-node gather
// ===========================================================================
__global__ __launch_bounds__(256)
void gat_transform(const float* __restrict__ X, const float* __restrict__ W,
                   const float* __restrict__ asrc, const float* __restrict__ adst,
                   float* __restrict__ Hout, float* __restrict__ es, float* __restrict__ ed,
                   int n)
{
  __shared__ float sX[64*LDH];
  const int tid = threadIdx.x;
  const long base = (long)blockIdx.x * 64;
  for (int i = tid; i < 64*32; i += 256){
    int row = i >> 5, q = i & 31;
    long gr = base + row;
    float4 v = make_float4(0.f, 0.f, 0.f, 0.f);
    if (gr < n) v = ((const float4*)(X + gr*HSZ))[q];
    ((float4*)(sX + row*LDH))[q] = v;
  }
  __syncthreads();
  const int rp = tid >> 3, dg = tid & 7;
  const int r0 = rp*2, r1 = r0 + 1;
  const float4* xa = (const float4*)(sX + r0*LDH);
  const float4* xb = (const float4*)(sX + r1*LDH);
  float ps0=0.f, pd0=0.f, ps1=0.f, pd1=0.f;
  for (int dd = 0; dd < 16; ++dd){
    const int cidx = dg*16 + dd;
    const float4* wp = (const float4*)(W + cidx*HSZ);
    float a0 = 0.f, a1 = 0.f;
    #pragma unroll 4
    for (int q = 0; q < 32; ++q){
      float4 w = wp[q];
      a0 += dot4f(w, xa[q]);
      a1 += dot4f(w, xb[q]);
    }
    float s = asrc[cidx], dv = adst[cidx];
    ps0 += a0*s; pd0 += a0*dv;
    ps1 += a1*s; pd1 += a1*dv;
    if (base + r0 < n) Hout[(base+r0)*HSZ + cidx] = a0;
    if (base + r1 < n) Hout[(base+r1)*HSZ + cidx] = a1;
  }
  #pragma unroll
  for (int m = 1; m < 8; m <<= 1){
    ps0 += __shfl_xor(ps0, m, 64);
    pd0 += __shfl_xor(pd0, m, 64);
    ps1 += __shfl_xor(ps1, m, 64);
    pd1 += __shfl_xor(pd1, m, 64);
  }
  if (dg == 0){
    if (base + r0 < n){ es[base+r0] = ps0; ed[base+r0] = pd0; }
    if (base + r1 < n){ es[base+r1] = ps1; ed[base+r1] = pd1; }
  }
}

__global__ void zero_i(int* __restrict__ p, int n)
{
  int i = blockIdx.x*256 + threadIdx.x;
  if (i < n) p[i] = 0;
}

__global__ void csr_count(const int* __restrict__ key, int* __restrict__ cnt, int E)
{
  int i = blockIdx.x*256 + threadIdx.x;
  if (i < E) atomicAdd(&cnt[key[i]], 1);
}

// single block, 1024 threads: exclusive scan of cnt[0..n) -> rowptr, cursor
__global__ __launch_bounds__(1024)
void csr_scan(const int* __restrict__ cnt, int* __restrict__ rowptr,
              int* __restrict__ cursor, int n)
{
  __shared__ int ls[1024];
  const int t = threadIdx.x;
  const int base = t*20;
  int loc[20];
  int s = 0;
  #pragma unroll
  for (int k = 0; k < 20; ++k){
    int idx = base + k;
    int v = (idx < n) ? cnt[idx] : 0;
    loc[k] = s; s += v;
  }
  ls[t] = s;
  __syncthreads();
  for (int off = 1; off < 1024; off <<= 1){
    int v = (t >= off) ? ls[t-off] : 0;
    __syncthreads();
    ls[t] += v;
    __syncthreads();
  }
  int excl = (t == 0) ? 0 : ls[t-1];
  #pragma unroll
  for (int k = 0; k < 20; ++k){
    int idx = base + k;
    if (idx < n){ int rp = excl + loc[k]; rowptr[idx] = rp; cursor[idx] = rp; }
  }
  if (t == 1023) rowptr[n] = ls[1023];
}

// val==nullptr -> store the element index i (used for sector row lists)
__global__ void csr_fill(const int* __restrict__ val, const int* __restrict__ key,
                         int* __restrict__ cursor, int* __restrict__ outl, int E)
{
  int i = blockIdx.x*256 + threadIdx.x;
  if (i >= E) return;
  int p = atomicAdd(&cursor[key[i]], 1);
  outl[p] = val ? val[i] : i;
}

// one wave per destination node: leaky-relu logits, max, denom, weighted gather
__global__ __launch_bounds__(256)
void gat_gather(const int* __restrict__ rowptr, const int* __restrict__ csrc,
                const float* __restrict__ es, const float* __restrict__ ed,
                const float* __restrict__ Hv, const float* __restrict__ bias,
                float* __restrict__ out, int n)
{
  int d = blockIdx.x*4 + (threadIdx.x >> 6);
  int l = threadIdx.x & 63;
  if (d >= n) return;
  const int p0 = rowptr[d], p1 = rowptr[d+1];
  const float edd = ed[d];
  float eself = es[d] + edd;
  eself = eself > 0.f ? eself : 0.2f*eself;
  float m = eself;
  for (int j = p0 + l; j < p1; j += 64){
    int s = csrc[j];
    float e = es[s] + edd;
    e = e > 0.f ? e : 0.2f*e;
    m = fmaxf(m, e);
  }
  #pragma unroll
  for (int off = 1; off < 64; off <<= 1) m = fmaxf(m, __shfl_xor(m, off, 64));
  float part = 0.f;
  for (int j = p0 + l; j < p1; j += 64){
    int s = csrc[j];
    float e = es[s] + edd;
    e = e > 0.f ? e : 0.2f*e;
    part += __expf(e - m);
  }
  #pragma unroll
  for (int off = 1; off < 64; off <<= 1) part += __shfl_xor(part, off, 64);
  const float wself = __expf(eself - m);
  const float inv = 1.f/(part + wself);
  float a = wself*inv;
  float acc0 = a * Hv[(long)d*HSZ + l];
  float acc1 = a * Hv[(long)d*HSZ + 64 + l];
  for (int j = p0; j < p1; ++j){
    int s = csrc[j];
    float e = es[s] + edd;
    e = e > 0.f ? e : 0.2f*e;
    float al = __expf(e - m)*inv;
    acc0 += al * Hv[(long)s*HSZ + l];
    acc1 += al * Hv[(long)s*HSZ + 64 + l];
  }
  out[(long)d*HSZ + l]      = acc0 + bias[l];
  out[(long)d*HSZ + 64 + l] = acc1 + bias[64 + l];
}

// per-sector max pool using sector row-list (CSR over sid)
__global__ __launch_bounds__(256)
void sector_pool(const float* __restrict__ intra, const int* __restrict__ srowptr,
                 const int* __restrict__ slist, float* __restrict__ spool)
{
  const int sec = blockIdx.x;
  const int t = threadIdx.x;
  const int d = t & 127, half = t >> 7;
  const int p0 = srowptr[sec], p1 = srowptr[sec+1];
  float m = -3.402823466e+38f;
  for (int j = p0 + half; j < p1; j += 2){
    int r = slist[j];
    m = fmaxf(m, intra[(long)r*HSZ + d]);
  }
  __shared__ float red[256];
  red[t] = m;
  __syncthreads();
  if (half == 0) spool[sec*HSZ + d] = fmaxf(red[d], red[128 + d]);
}

// ---- inter-sector GAT (tiny, keep atomic path) ----
__global__ void gat_init(unsigned* __restrict__ maxb, float* __restrict__ den,
                         float* __restrict__ acc, int n)
{
  long i = (long)blockIdx.x*256 + threadIdx.x;
  if (i < n){ maxb[i] = NEG_MAX_ORD; den[i] = 0.f; }
  if (i < (long)n*HSZ) acc[i] = 0.f;
}

__global__ void edge_max(const int* __restrict__ src, const int* __restrict__ dst,
                         const float* __restrict__ es, const float* __restrict__ ed,
                         unsigned* __restrict__ maxb, int E, int n)
{
  int i = blockIdx.x*256 + threadIdx.x;
  if (i >= E + n) return;
  int s, d;
  if (i < E){ s = src[i]; d = dst[i]; } else { s = d = i - E; }
  float e = es[s] + ed[d];
  e = e > 0.f ? e : 0.2f*e;
  atomicMax(maxb + d, fordu(e));
}

__global__ void edge_sum(const int* __restrict__ src, const int* __restrict__ dst,
                         const float* __restrict__ es, const float* __restrict__ ed,
                         const unsigned* __restrict__ maxb, float* __restrict__ den,
                         float* __restrict__ wbuf, int E, int n)
{
  int i = blockIdx.x*256 + threadIdx.x;
  if (i >= E + n) return;
  int s, d;
  if (i < E){ s = src[i]; d = dst[i]; } else { s = d = i - E; }
  float e = es[s] + ed[d];
  e = e > 0.f ? e : 0.2f*e;
  float w = __expf(e - unfordu(maxb[d]));
  wbuf[i] = w;
  atomicAdd(den + d, w);
}

__global__ void edge_scatter(const int* __restrict__ src, const int* __restrict__ dst,
                             const float* __restrict__ wbuf, const float* __restrict__ den,
                             const float* __restrict__ Hv, float* __restrict__ acc,
                             int E, int n)
{
  long t = (long)blockIdx.x*256 + threadIdx.x;
  long i = t >> 5;
  int  j = (int)(t & 31);
  if (i >= E + n) return;
  int s, d;
  if (i < E){ s = src[i]; d = dst[i]; } else { s = d = (int)(i - E); }
  float alpha = wbuf[i] / den[d];
  float4 hv = ((const float4*)(Hv + (long)s*HSZ))[j];
  float* o = acc + (long)d*HSZ + j*4;
  atomicAdd(o+0, alpha*hv.x);
  atomicAdd(o+1, alpha*hv.y);
  atomicAdd(o+2, alpha*hv.z);
  atomicAdd(o+3, alpha*hv.w);
}

__global__ void inter_bias_k(const float* __restrict__ acc2, const float* __restrict__ bias,
                             float* __restrict__ isec)
{
  int i = blockIdx.x*256 + threadIdx.x;   // exactly 64*128
  isec[i] = acc2[i] + bias[i & 127];
}

__global__ __launch_bounds__(256)
void fusion_k(const float* __restrict__ seq, const float* __restrict__ intra,
              const float* __restrict__ isec, const int* __restrict__ sid,
              const float* __restrict__ fw, const float* __restrict__ fb,
              float* __restrict__ out, int n)
{
  int i = blockIdx.x*4 + (threadIdx.x >> 6);
  int l = threadIdx.x & 63;
  if (i >= n) return;
  int sc = sid[i];
  long b = (long)i*HSZ;
  long sb = (long)sc*HSZ;
  float acc = fw[l]     * seq[b + l]      + fw[64 + l]  * seq[b + 64 + l]
            + fw[128+l] * intra[b + l]    + fw[192 + l] * intra[b + 64 + l]
            + fw[256+l] * isec[sb + l]    + fw[320 + l] * isec[sb + 64 + l];
  #pragma unroll
  for (int m = 1; m < 64; m <<= 1) acc += __shfl_xor(acc, m, 64);
  if (l == 0) out[i] = acc + fb[0];
}

extern "C" void kernel_launch(void* const* d_in, const int* in_sizes, int n_in,
                              void* d_out, int out_size, void* d_ws, size_t ws_size,
                              hipStream_t stream)
{
  const float* x    = (const float*)d_in[0];
  const int*   iei  = (const int*)d_in[1];    // [2, 640000]
  const int*   eei  = (const int*)d_in[2];    // [2, 4096]
  const int*   sid  = (const int*)d_in[3];
  const float* wih0 = (const float*)d_in[4];
  const float* whh0 = (const float*)d_in[5];
  const float* bih0 = (const float*)d_in[6];
  const float* bhh0 = (const float*)d_in[7];
  const float* wih1 = (const float*)d_in[8];
  const float* whh1 = (const float*)d_in[9];
  const float* bih1 = (const float*)d_in[10];
  const float* bhh1 = (const float*)d_in[11];
  const float* iW   = (const float*)d_in[12];
  const float* ias  = (const float*)d_in[13];
  const float* iad  = (const float*)d_in[14];
  const float* ib   = (const float*)d_in[15];
  const float* eW   = (const float*)d_in[16];
  const float* eas  = (const float*)d_in[17];
  const float* ead  = (const float*)d_in[18];
  const float* eb   = (const float*)d_in[19];
  const float* fW   = (const float*)d_in[20];
  const float* fb   = (const float*)d_in[21];

  float* ws = (float*)d_ws;
  long off = 0;
  float* seq    = ws + off; off += 2560000;
  float* hintra = ws + off; off += 2560000;
  float* intra  = ws + off; off += 2560000;
  float* es     = ws + off; off += 20000;
  float* ed     = ws + off; off += 20000;
  int*   cnt    = (int*)(ws + off); off += 20000;
  int*   rowptr = (int*)(ws + off); off += 20004;
  int*   cursor = (int*)(ws + off); off += 20000;
  int*   csrc   = (int*)(ws + off); off += 640000;
  int*   scnt    = (int*)(ws + off); off += 64;
  int*   srowptr = (int*)(ws + off); off += 68;
  int*   scursor = (int*)(ws + off); off += 64;
  int*   slist   = (int*)(ws + off); off += 20000;
  float* w0p = ws + off; off += 24576;   // bf16x3 pack: 2kt*24nt*2*1024B
  float* u0p = ws + off; off += 49152;   // 4kt
  float* w1p = ws + off; off += 49152;
  float* u1p = ws + off; off += 49152;
  float* spool  = ws + off; off += 8192;
  float* hinter = ws + off; off += 8192;
  float* acc2   = ws + off; off += 8192;
  float* es2    = ws + off; off += 64;
  float* ed2    = ws + off; off += 64;
  unsigned* mx2 = (unsigned*)(ws + off); off += 64;
  float* den2   = ws + off; off += 64;
  float* wbf2   = ws + off; off += 4160;
  float* isec   = ws + off; off += 8192;
  // total ~8.6M floats = ~34.5 MB

  // 0) pack GRU weights into bf16 hi/lo MFMA fragment layout
  wpack_mfma<<<12, 256, 0, stream>>>(wih0, (unsigned short*)w0p, 64);
  wpack_mfma<<<24, 256, 0, stream>>>(whh0, (unsigned short*)u0p, 128);
  wpack_mfma<<<24, 256, 0, stream>>>(wih1, (unsigned short*)w1p, 128);
  wpack_mfma<<<24, 256, 0, stream>>>(whh1, (unsigned short*)u1p, 128);

  // 1) MFMA bf16x3 fused 2-layer GRU -> seq_emb (1250 blocks x 128 thr)
  gru_mfma<<<1250, 128, 0, stream>>>(x,
                                     (const unsigned short*)w0p, (const unsigned short*)u0p,
                                     (const unsigned short*)w1p, (const unsigned short*)u1p,
                                     bih0, bhh0, bih1, bhh1, seq);

  // 2) intra GAT: transform + CSR build + atomic-free gather
  gat_transform<<<313, 256, 0, stream>>>(seq, iW, ias, iad, hintra, es, ed, NCOMP);
  zero_i   <<<(NCOMP+255)/256, 256, 0, stream>>>(cnt, NCOMP);
  zero_i   <<<1, 256, 0, stream>>>(scnt, NSEC);
  csr_count<<<(EINTRA+255)/256, 256, 0, stream>>>(iei + EINTRA, cnt, EINTRA);
  csr_count<<<(NCOMP+255)/256, 256, 0, stream>>>(sid, scnt, NCOMP);
  csr_scan <<<1, 1024, 0, stream>>>(cnt, rowptr, cursor, NCOMP);
  csr_scan <<<1, 1024, 0, stream>>>(scnt, srowptr, scursor, NSEC);
  csr_fill <<<(EINTRA+255)/256, 256, 0, stream>>>(iei, iei + EINTRA, cursor, csrc, EINTRA);
  csr_fill <<<(NCOMP+255)/256, 256, 0, stream>>>(nullptr, sid, scursor, slist, NCOMP);
  gat_gather<<<NCOMP/4, 256, 0, stream>>>(rowptr, csrc, es, ed, hintra, ib, intra, NCOMP);

  // 3) per-sector max pool via sector row lists
  sector_pool<<<NSEC, 256, 0, stream>>>(intra, srowptr, slist, spool);

  // 4) inter GAT (tiny: 64 nodes, 4096 edges — atomic path)
  gat_init<<<32, 256, 0, stream>>>(mx2, den2, acc2, NSEC);
  gat_transform<<<1, 256, 0, stream>>>(spool, eW, eas, ead, hinter, es2, ed2, NSEC);
  {
    int tot = EINTER + NSEC;
    edge_max    <<<(tot+255)/256, 256, 0, stream>>>(eei, eei+EINTER, es2, ed2, mx2, EINTER, NSEC);
    edge_sum    <<<(tot+255)/256, 256, 0, stream>>>(eei, eei+EINTER, es2, ed2, mx2, den2, wbf2, EINTER, NSEC);
    edge_scatter<<<(tot*32)/256, 256, 0, stream>>>(eei, eei+EINTER, wbf2, den2, hinter, acc2, EINTER, NSEC);
  }
  inter_bias_k<<<32, 256, 0, stream>>>(acc2, eb, isec);

  // 5) fusion -> output [20000]
  fusion_k<<<NCOMP/4, 256, 0, stream>>>(seq, intra, isec, sid, fW, fb, (float*)d_out, NCOMP);
}

// Round 6
// 2944.176 us; speedup vs baseline: 2.6569x; 2.6569x over previous
//
#include <hip/hip_runtime.h>
#include <math.h>

// Problem constants
#define NCOMP 20000
#define SEQT  32
#define INSZ  64
#define HSZ   128
#define EINTRA 640000
#define EINTER 4096
#define NSEC  64

#define LDH 132   // padded LDS row stride (floats) for gat_transform

typedef __attribute__((ext_vector_type(8))) short bf16x8;   // 8 bf16 in 4 VGPRs
typedef __attribute__((ext_vector_type(4))) float f32x4;    // MFMA C/D frag

__device__ __forceinline__ float dot4f(float4 a, float4 b){
  return a.x*b.x + a.y*b.y + a.z*b.z + a.w*b.w;
}
__device__ __forceinline__ float sigm(float x){ return 1.f/(1.f + __expf(-x)); }
__device__ __forceinline__ float ftanh(float x){
  float cx = fminf(fmaxf(x, -15.f), 15.f);
  float e = __expf(2.f*cx);
  return (e - 1.f)/(e + 1.f);
}
// monotone float<->uint mapping so atomicMax works for signed floats (inter path)
__device__ __forceinline__ unsigned fordu(float f){
  unsigned b = __float_as_uint(f);
  return (b & 0x80000000u) ? ~b : (b | 0x80000000u);
}
__device__ __forceinline__ float unfordu(unsigned u){
  unsigned b = (u & 0x80000000u) ? (u & 0x7fffffffu) : ~u;
  return __uint_as_float(b);
}
#define NEG_MAX_ORD 0x00800000u   // fordu(-FLT_MAX)

// bf16 hi/lo split helpers (truncation split: w = hi + rem exactly, lo = bf16(rem))
__device__ __forceinline__ unsigned short bf16hi(float f){
  return (unsigned short)(__float_as_uint(f) >> 16);
}
__device__ __forceinline__ float bf16tof(unsigned short h){
  return __uint_as_float(((unsigned)h) << 16);
}

// ===========================================================================
// Weight packing for MFMA bf16x3: out[(kt*24+nt)*2+{hi,lo}][lane][8 bf16].
// Fragment convention (must match A-side): col n = lane&15 (within nt tile),
// k = kt*32 + (lane>>4)*8 + j.  One coalesced dwordx4 per fragment at use.
// (UNCHANGED from round 5 — layout verified correct by the passing refcheck.)
// ===========================================================================
__global__ void wpack_mfma(const float* __restrict__ W, unsigned short* __restrict__ out, int K)
{
  int tid = blockIdx.x*256 + threadIdx.x;
  int KT = K >> 5;
  if (tid >= KT*24*64) return;
  int lane = tid & 63;
  int nt   = (tid >> 6) % 24;
  int kt   = (tid >> 6) / 24;
  int col  = nt*16 + (lane & 15);
  int kbase = kt*32 + (lane >> 4)*8;
  size_t b = ((size_t)(kt*24 + nt)*2*64 + lane)*8;   // hi at b, lo at b+512
  #pragma unroll
  for (int j = 0; j < 8; ++j){
    float w = W[(size_t)col*K + kbase + j];
    unsigned short h = bf16hi(w);
    float rem = w - bf16tof(h);
    out[b + j]       = h;
    out[b + 512 + j] = bf16hi(rem);
  }
}

// ===========================================================================
// MFMA bf16x3 fused 2-layer GRU, v2: weight-reuse restructure.
// Block = 640 thr (10 waves) = 80 companies (5 M-tiles), grid 250 (exact).
// Wave w: mtile mt=w>>1, dim-half dh=w&1 (owns dims [64dh, 64dh+64) of all
// gates for comps [mt*16, mt*16+16)). Round-5 diagnosis: 1250 blocks each
// re-streamed 672KB of B-fragments per t (27GB demand, 12.2GB L2 miss, both
// pipes <5% busy). 5x fewer blocks => 5x less B traffic; the 5 waves sharing
// a dh read identical B addresses => L1 dedup. h kept in A-FRAGMENT layout
// (hfr[layer][hi/lo][kt][mt][lane][8]) so LOADA = 2 lane-sequential
// ds_read_b128 (round 5's 16x ds_read_u16 @256B stride = 6.1e7 conflicts).
// Math identical to round 5 (bf16x3: AhBh+AhBl+AlBh into fp32 C).
// ===========================================================================
__global__ __launch_bounds__(640, 2)
void gru_mfma(const float* __restrict__ x,
              const unsigned short* __restrict__ w0pk, const unsigned short* __restrict__ u0pk,
              const unsigned short* __restrict__ w1pk, const unsigned short* __restrict__ u1pk,
              const float* __restrict__ bih0, const float* __restrict__ bhh0,
              const float* __restrict__ bih1, const float* __restrict__ bhh1,
              float* __restrict__ seq)
{
  // [layer][hi/lo][kt][mtile][lane][8] : 2*2*4*5*64*8*2B = 80 KB
  __shared__ __align__(16) unsigned short hfr[2][2][4][5][64][8];
  __shared__ float bias[1024];  // [0:128)R0 [128:256)Z0 [256:384)NX0 [384:512)NH0, +512 layer1

  const int tid  = threadIdx.x;
  const int wave = tid >> 6, l = tid & 63;
  const int cq = l & 15, kg = l >> 4;
  const int mt = wave >> 1;                 // 0..4  M-tile within block
  const int dh = wave & 1;                  // dim half: dims [64dh, 64dh+64)
  const int sbase = dh*4;                   // N-tile base per gate
  const int cbase = blockIdx.x*80;          // 250*80 == 20000 exactly
  const int comp0 = cbase + mt*16;          // this wave's company base

  // stage biases (merged R/Z, split NX/NH) + zero h state; one barrier
  for (int i = tid; i < 1024; i += 640){
    float v;
    if      (i <  256) v = bih0[i] + bhh0[i];
    else if (i <  384) v = bih0[i];             // 256+(i-256)
    else if (i <  512) v = bhh0[i - 128];       // 256+(i-384)
    else if (i <  768) v = bih1[i - 512] + bhh1[i - 512];
    else if (i <  896) v = bih1[i - 512];       // 256+(i-768)
    else               v = bhh1[i - 640];       // 256+(i-896)
    bias[i] = v;
  }
  {
    float4 z4 = make_float4(0.f,0.f,0.f,0.f);
    float4* hz = (float4*)&hfr[0][0][0][0][0][0];
    for (int i = tid; i < 5120; i += 640) hz[i] = z4;   // 80 KB
  }
  __syncthreads();

  // ---- macros (kept as macros so all C-frag indexing stays static => regs) ----
  #define CINIT(BOFS) do { \
    _Pragma("unroll") for (int s = 0; s < 4; ++s){ \
      float b0 = bias[(BOFS)       + (sbase+s)*16 + cq]; \
      float b1 = bias[(BOFS) + 128 + (sbase+s)*16 + cq]; \
      float b2 = bias[(BOFS) + 256 + (sbase+s)*16 + cq]; \
      float b3 = bias[(BOFS) + 384 + (sbase+s)*16 + cq]; \
      crz[s]   = (f32x4){b0,b0,b0,b0}; \
      crz[4+s] = (f32x4){b1,b1,b1,b1}; \
      cnx[s]   = (f32x4){b2,b2,b2,b2}; \
      cnh[s]   = (f32x4){b3,b3,b3,b3}; } \
  } while(0)

  // A-frag load: two conflict-free lane-sequential ds_read_b128
  #define LOADA(LYR, KT, AH, AL) do { \
    AH = *(const bf16x8*)&hfr[LYR][0][KT][mt][l][0]; \
    AL = *(const bf16x8*)&hfr[LYR][1][KT][mt][l][0]; \
  } while(0)

  #define MF3(AH, AL, BH, BL, C) do { \
    C = __builtin_amdgcn_mfma_f32_16x16x32_bf16(AH, BH, C, 0,0,0); \
    C = __builtin_amdgcn_mfma_f32_16x16x32_bf16(AH, BL, C, 0,0,0); \
    C = __builtin_amdgcn_mfma_f32_16x16x32_bf16(AL, BH, C, 0,0,0); \
  } while(0)

  #define GEMM12(PK, KT, AH, AL, CN) do { \
    const unsigned short* _p = (PK) + (size_t)(KT)*24*1024 + (size_t)l*8; \
    _Pragma("unroll") for (int s = 0; s < 4; ++s){ \
      { const bf16x8* bp = (const bf16x8*)(_p + (size_t)(sbase+s)*1024); \
        bf16x8 bh = bp[0], bl = bp[64]; MF3(AH, AL, bh, bl, crz[s]); } \
      { const bf16x8* bp = (const bf16x8*)(_p + (size_t)(8 + sbase+s)*1024); \
        bf16x8 bh = bp[0], bl = bp[64]; MF3(AH, AL, bh, bl, crz[4+s]); } \
      { const bf16x8* bp = (const bf16x8*)(_p + (size_t)(16 + sbase+s)*1024); \
        bf16x8 bh = bp[0], bl = bp[64]; MF3(AH, AL, bh, bl, CN[s]); } } \
  } while(0)

  // Elementwise GRU update. C/D layout: col(=dim-in-tile)=cq, row(=comp)=kg*4+r.
  // h_old read + h_new write go to the A-frag layout cell for (comp, dim):
  //   kt'=d>>5, lane'=((d>>3)&3)*16 + comp_in_tile, j'=d&7.
  #define ELEM(LYR, DOSTORE) do { \
    _Pragma("unroll") for (int s = 0; s < 4; ++s){ \
      int d  = dh*64 + s*16 + cq; \
      int ktp = d >> 5, kgp = (d >> 3) & 3, jp = d & 7; \
      unsigned short* hhi = &hfr[LYR][0][ktp][mt][0][0]; \
      unsigned short* hlo = &hfr[LYR][1][ktp][mt][0][0]; \
      unsigned short nh_[4], nl_[4]; float hnv[4]; \
      _Pragma("unroll") for (int r = 0; r < 4; ++r){ \
        int lanep = kgp*16 + kg*4 + r; \
        float hold = bf16tof(hhi[lanep*8 + jp]) + bf16tof(hlo[lanep*8 + jp]); \
        float rr = sigm(crz[s][r]); \
        float zz = sigm(crz[4+s][r]); \
        float nn = ftanh(cnx[s][r] + rr*cnh[s][r]); \
        float hn = (1.f - zz)*nn + zz*hold; \
        unsigned short hh = bf16hi(hn); \
        nh_[r] = hh; nl_[r] = bf16hi(hn - bf16tof(hh)); hnv[r] = hn; } \
      _Pragma("unroll") for (int r = 0; r < 4; ++r){ \
        int lanep = kgp*16 + kg*4 + r; \
        hhi[lanep*8 + jp] = nh_[r]; \
        hlo[lanep*8 + jp] = nl_[r]; } \
      if (DOSTORE){ \
        _Pragma("unroll") for (int r = 0; r < 4; ++r) \
          seq[(size_t)(comp0 + kg*4 + r)*HSZ + d] = hnv[r]; } } \
  } while(0)

  #pragma unroll 1
  for (int t = 0; t < SEQT; ++t){
    f32x4 crz[8], cnx[4], cnh[4];
    // ================= layer 0 =================
    CINIT(0);
    #pragma unroll
    for (int kt = 0; kt < 2; ++kt){           // x part, K=64 (A direct from global)
      const float* xp = x + ((size_t)(comp0 + cq)*SEQT + t)*INSZ + kt*32 + kg*8;
      float4 q0 = *(const float4*)xp;
      float4 q1 = *(const float4*)(xp + 4);
      float xf[8] = {q0.x,q0.y,q0.z,q0.w, q1.x,q1.y,q1.z,q1.w};
      bf16x8 ah, al;
      #pragma unroll
      for (int j = 0; j < 8; ++j){
        unsigned short h = bf16hi(xf[j]);
        ah[j] = (short)h;
        al[j] = (short)bf16hi(xf[j] - bf16tof(h));
      }
      GEMM12(w0pk, kt, ah, al, cnx);
    }
    #pragma unroll 2
    for (int kt = 0; kt < 4; ++kt){           // h part, K=128 (A from LDS h0)
      bf16x8 ah, al; LOADA(0, kt, ah, al);
      GEMM12(u0pk, kt, ah, al, cnh);
    }
    __syncthreads();                           // all waves done reading h0_old
    ELEM(0, false);
    __syncthreads();                           // h0_new visible
    // ================= layer 1 =================
    CINIT(512);
    #pragma unroll 2
    for (int kt = 0; kt < 4; ++kt){           // input = h0_new
      bf16x8 ah, al; LOADA(0, kt, ah, al);
      GEMM12(w1pk, kt, ah, al, cnx);
    }
    #pragma unroll 2
    for (int kt = 0; kt < 4; ++kt){           // hidden h1_old
      bf16x8 ah, al; LOADA(1, kt, ah, al);
      GEMM12(u1pk, kt, ah, al, cnh);
    }
    __syncthreads();                           // all waves done reading h1_old
    ELEM(1, (t == SEQT-1));
    __syncthreads();                           // h1_new visible for next t
  }
  #undef CINIT
  #undef LOADA
  #undef MF3
  #undef GEMM12
  #undef ELEM
}

// ===========================================================================
// GAT stage — CSR build + atomic-free per-node gather
// ===========================================================================
__global__ __launch_bounds__(256)
void gat_transform(const float* __restrict__ X, const float* __restrict__ W,
                   const float* __restrict__ asrc, const float* __restrict__ adst,
                   float* __restrict__ Hout, float* __restrict__ es, float* __restrict__ ed,
                   int n)
{
  __shared__ float sX[64*LDH];
  const int tid = threadIdx.x;
  const long base = (long)blockIdx.x * 64;
  for (int i = tid; i < 64*32; i += 256){
    int row = i >> 5, q = i & 31;
    long gr = base + row;
    float4 v = make_float4(0.f, 0.f, 0.f, 0.f);
    if (gr < n) v = ((const float4*)(X + gr*HSZ))[q];
    ((float4*)(sX + row*LDH))[q] = v;
  }
  __syncthreads();
  const int rp = tid >> 3, dg = tid & 7;
  const int r0 = rp*2, r1 = r0 + 1;
  const float4* xa = (const float4*)(sX + r0*LDH);
  const float4* xb = (const float4*)(sX + r1*LDH);
  float ps0=0.f, pd0=0.f, ps1=0.f, pd1=0.f;
  for (int dd = 0; dd < 16; ++dd){
    const int cidx = dg*16 + dd;
    const float4* wp = (const float4*)(W + cidx*HSZ);
    float a0 = 0.f, a1 = 0.f;
    #pragma unroll 4
    for (int q = 0; q < 32; ++q){
      float4 w = wp[q];
      a0 += dot4f(w, xa[q]);
      a1 += dot4f(w, xb[q]);
    }
    float s = asrc[cidx], dv = adst[cidx];
    ps0 += a0*s; pd0 += a0*dv;
    ps1 += a1*s; pd1 += a1*dv;
    if (base + r0 < n) Hout[(base+r0)*HSZ + cidx] = a0;
    if (base + r1 < n) Hout[(base+r1)*HSZ + cidx] = a1;
  }
  #pragma unroll
  for (int m = 1; m < 8; m <<= 1){
    ps0 += __shfl_xor(ps0, m, 64);
    pd0 += __shfl_xor(pd0, m, 64);
    ps1 += __shfl_xor(ps1, m, 64);
    pd1 += __shfl_xor(pd1, m, 64);
  }
  if (dg == 0){
    if (base + r0 < n){ es[base+r0] = ps0; ed[base+r0] = pd0; }
    if (base + r1 < n){ es[base+r1] = ps1; ed[base+r1] = pd1; }
  }
}

__global__ void zero_i(int* __restrict__ p, int n)
{
  int i = blockIdx.x*256 + threadIdx.x;
  if (i < n) p[i] = 0;
}

__global__ void csr_count(const int* __restrict__ key, int* __restrict__ cnt, int E)
{
  int i = blockIdx.x*256 + threadIdx.x;
  if (i < E) atomicAdd(&cnt[key[i]], 1);
}

// single block, 1024 threads: exclusive scan of cnt[0..n) -> rowptr, cursor
__global__ __launch_bounds__(1024)
void csr_scan(const int* __restrict__ cnt, int* __restrict__ rowptr,
              int* __restrict__ cursor, int n)
{
  __shared__ int ls[1024];
  const int t = threadIdx.x;
  const int base = t*20;
  int loc[20];
  int s = 0;
  #pragma unroll
  for (int k = 0; k < 20; ++k){
    int idx = base + k;
    int v = (idx < n) ? cnt[idx] : 0;
    loc[k] = s; s += v;
  }
  ls[t] = s;
  __syncthreads();
  for (int off = 1; off < 1024; off <<= 1){
    int v = (t >= off) ? ls[t-off] : 0;
    __syncthreads();
    ls[t] += v;
    __syncthreads();
  }
  int excl = (t == 0) ? 0 : ls[t-1];
  #pragma unroll
  for (int k = 0; k < 20; ++k){
    int idx = base + k;
    if (idx < n){ int rp = excl + loc[k]; rowptr[idx] = rp; cursor[idx] = rp; }
  }
  if (t == 1023) rowptr[n] = ls[1023];
}

// val==nullptr -> store the element index i (used for sector row lists)
__global__ void csr_fill(const int* __restrict__ val, const int* __restrict__ key,
                         int* __restrict__ cursor, int* __restrict__ outl, int E)
{
  int i = blockIdx.x*256 + threadIdx.x;
  if (i >= E) return;
  int p = atomicAdd(&cursor[key[i]], 1);
  outl[p] = val ? val[i] : i;
}

// one wave per destination node: leaky-relu logits, max, denom, weighted gather
__global__ __launch_bounds__(256)
void gat_gather(const int* __restrict__ rowptr, const int* __restrict__ csrc,
                const float* __restrict__ es, const float* __restrict__ ed,
                const float* __restrict__ Hv, const float* __restrict__ bias,
                float* __restrict__ out, int n)
{
  int d = blockIdx.x*4 + (threadIdx.x >> 6);
  int l = threadIdx.x & 63;
  if (d >= n) return;
  const int p0 = rowptr[d], p1 = rowptr[d+1];
  const float edd = ed[d];
  float eself = es[d] + edd;
  eself = eself > 0.f ? eself : 0.2f*eself;
  float m = eself;
  for (int j = p0 + l; j < p1; j += 64){
    int s = csrc[j];
    float e = es[s] + edd;
    e = e > 0.f ? e : 0.2f*e;
    m = fmaxf(m, e);
  }
  #pragma unroll
  for (int off = 1; off < 64; off <<= 1) m = fmaxf(m, __shfl_xor(m, off, 64));
  float part = 0.f;
  for (int j = p0 + l; j < p1; j += 64){
    int s = csrc[j];
    float e = es[s] + edd;
    e = e > 0.f ? e : 0.2f*e;
    part += __expf(e - m);
  }
  #pragma unroll
  for (int off = 1; off < 64; off <<= 1) part += __shfl_xor(part, off, 64);
  const float wself = __expf(eself - m);
  const float inv = 1.f/(part + wself);
  float a = wself*inv;
  float acc0 = a * Hv[(long)d*HSZ + l];
  float acc1 = a * Hv[(long)d*HSZ + 64 + l];
  for (int j = p0; j < p1; ++j){
    int s = csrc[j];
    float e = es[s] + edd;
    e = e > 0.f ? e : 0.2f*e;
    float al = __expf(e - m)*inv;
    acc0 += al * Hv[(long)s*HSZ + l];
    acc1 += al * Hv[(long)s*HSZ + 64 + l];
  }
  out[(long)d*HSZ + l]      = acc0 + bias[l];
  out[(long)d*HSZ + 64 + l] = acc1 + bias[64 + l];
}

// per-sector max pool using sector row-list (CSR over sid)
__global__ __launch_bounds__(256)
void sector_pool(const float* __restrict__ intra, const int* __restrict__ srowptr,
                 const int* __restrict__ slist, float* __restrict__ spool)
{
  const int sec = blockIdx.x;
  const int t = threadIdx.x;
  const int d = t & 127, half = t >> 7;
  const int p0 = srowptr[sec], p1 = srowptr[sec+1];
  float m = -3.402823466e+38f;
  for (int j = p0 + half; j < p1; j += 2){
    int r = slist[j];
    m = fmaxf(m, intra[(long)r*HSZ + d]);
  }
  __shared__ float red[256];
  red[t] = m;
  __syncthreads();
  if (half == 0) spool[sec*HSZ + d] = fmaxf(red[d], red[128 + d]);
}

// ---- inter-sector GAT (tiny, keep atomic path) ----
__global__ void gat_init(unsigned* __restrict__ maxb, float* __restrict__ den,
                         float* __restrict__ acc, int n)
{
  long i = (long)blockIdx.x*256 + threadIdx.x;
  if (i < n){ maxb[i] = NEG_MAX_ORD; den[i] = 0.f; }
  if (i < (long)n*HSZ) acc[i] = 0.f;
}

__global__ void edge_max(const int* __restrict__ src, const int* __restrict__ dst,
                         const float* __restrict__ es, const float* __restrict__ ed,
                         unsigned* __restrict__ maxb, int E, int n)
{
  int i = blockIdx.x*256 + threadIdx.x;
  if (i >= E + n) return;
  int s, d;
  if (i < E){ s = src[i]; d = dst[i]; } else { s = d = i - E; }
  float e = es[s] + ed[d];
  e = e > 0.f ? e : 0.2f*e;
  atomicMax(maxb + d, fordu(e));
}

__global__ void edge_sum(const int* __restrict__ src, const int* __restrict__ dst,
                         const float* __restrict__ es, const float* __restrict__ ed,
                         const unsigned* __restrict__ maxb, float* __restrict__ den,
                         float* __restrict__ wbuf, int E, int n)
{
  int i = blockIdx.x*256 + threadIdx.x;
  if (i >= E + n) return;
  int s, d;
  if (i < E){ s = src[i]; d = dst[i]; } else { s = d = i - E; }
  float e = es[s] + ed[d];
  e = e > 0.f ? e : 0.2f*e;
  float w = __expf(e - unfordu(maxb[d]));
  wbuf[i] = w;
  atomicAdd(den + d, w);
}

__global__ void edge_scatter(const int* __restrict__ src, const int* __restrict__ dst,
                             const float* __restrict__ wbuf, const float* __restrict__ den,
                             const float* __restrict__ Hv, float* __restrict__ acc,
                             int E, int n)
{
  long t = (long)blockIdx.x*256 + threadIdx.x;
  long i = t >> 5;
  int  j = (int)(t & 31);
  if (i >= E + n) return;
  int s, d;
  if (i < E){ s = src[i]; d = dst[i]; } else { s = d = (int)(i - E); }
  float alpha = wbuf[i] / den[d];
  float4 hv = ((const float4*)(Hv + (long)s*HSZ))[j];
  float* o = acc + (long)d*HSZ + j*4;
  atomicAdd(o+0, alpha*hv.x);
  atomicAdd(o+1, alpha*hv.y);
  atomicAdd(o+2, alpha*hv.z);
  atomicAdd(o+3, alpha*hv.w);
}

__global__ void inter_bias_k(const float* __restrict__ acc2, const float* __restrict__ bias,
                             float* __restrict__ isec)
{
  int i = blockIdx.x*256 + threadIdx.x;   // exactly 64*128
  isec[i] = acc2[i] + bias[i & 127];
}

__global__ __launch_bounds__(256)
void fusion_k(const float* __restrict__ seq, const float* __restrict__ intra,
              const float* __restrict__ isec, const int* __restrict__ sid,
              const float* __restrict__ fw, const float* __restrict__ fb,
              float* __restrict__ out, int n)
{
  int i = blockIdx.x*4 + (threadIdx.x >> 6);
  int l = threadIdx.x & 63;
  if (i >= n) return;
  int sc = sid[i];
  long b = (long)i*HSZ;
  long sb = (long)sc*HSZ;
  float acc = fw[l]     * seq[b + l]      + fw[64 + l]  * seq[b + 64 + l]
            + fw[128+l] * intra[b + l]    + fw[192 + l] * intra[b + 64 + l]
            + fw[256+l] * isec[sb + l]    + fw[320 + l] * isec[sb + 64 + l];
  #pragma unroll
  for (int m = 1; m < 64; m <<= 1) acc += __shfl_xor(acc, m, 64);
  if (l == 0) out[i] = acc + fb[0];
}

extern "C" void kernel_launch(void* const* d_in, const int* in_sizes, int n_in,
                              void* d_out, int out_size, void* d_ws, size_t ws_size,
                              hipStream_t stream)
{
  const float* x    = (const float*)d_in[0];
  const int*   iei  = (const int*)d_in[1];    // [2, 640000]
  const int*   eei  = (const int*)d_in[2];    // [2, 4096]
  const int*   sid  = (const int*)d_in[3];
  const float* wih0 = (const float*)d_in[4];
  const float* whh0 = (const float*)d_in[5];
  const float* bih0 = (const float*)d_in[6];
  const float* bhh0 = (const float*)d_in[7];
  const float* wih1 = (const float*)d_in[8];
  const float* whh1 = (const float*)d_in[9];
  const float* bih1 = (const float*)d_in[10];
  const float* bhh1 = (const float*)d_in[11];
  const float* iW   = (const float*)d_in[12];
  const float* ias  = (const float*)d_in[13];
  const float* iad  = (const float*)d_in[14];
  const float* ib   = (const float*)d_in[15];
  const float* eW   = (const float*)d_in[16];
  const float* eas  = (const float*)d_in[17];
  const float* ead  = (const float*)d_in[18];
  const float* eb   = (const float*)d_in[19];
  const float* fW   = (const float*)d_in[20];
  const float* fb   = (const float*)d_in[21];

  float* ws = (float*)d_ws;
  long off = 0;
  float* seq    = ws + off; off += 2560000;
  float* hintra = ws + off; off += 2560000;
  float* intra  = ws + off; off += 2560000;
  float* es     = ws + off; off += 20000;
  float* ed     = ws + off; off += 20000;
  int*   cnt    = (int*)(ws + off); off += 20000;
  int*   rowptr = (int*)(ws + off); off += 20004;
  int*   cursor = (int*)(ws + off); off += 20000;
  int*   csrc   = (int*)(ws + off); off += 640000;
  int*   scnt    = (int*)(ws + off); off += 64;
  int*   srowptr = (int*)(ws + off); off += 68;
  int*   scursor = (int*)(ws + off); off += 64;
  int*   slist   = (int*)(ws + off); off += 20000;
  float* w0p = ws + off; off += 24576;   // bf16x3 pack: 2kt*24nt*2*1024B
  float* u0p = ws + off; off += 49152;   // 4kt
  float* w1p = ws + off; off += 49152;
  float* u1p = ws + off; off += 49152;
  float* spool  = ws + off; off += 8192;
  float* hinter = ws + off; off += 8192;
  float* acc2   = ws + off; off += 8192;
  float* es2    = ws + off; off += 64;
  float* ed2    = ws + off; off += 64;
  unsigned* mx2 = (unsigned*)(ws + off); off += 64;
  float* den2   = ws + off; off += 64;
  float* wbf2   = ws + off; off += 4160;
  float* isec   = ws + off; off += 8192;
  // total ~8.6M floats = ~34.5 MB

  // 0) pack GRU weights into bf16 hi/lo MFMA fragment layout
  wpack_mfma<<<12, 256, 0, stream>>>(wih0, (unsigned short*)w0p, 64);
  wpack_mfma<<<24, 256, 0, stream>>>(whh0, (unsigned short*)u0p, 128);
  wpack_mfma<<<24, 256, 0, stream>>>(wih1, (unsigned short*)w1p, 128);
  wpack_mfma<<<24, 256, 0, stream>>>(whh1, (unsigned short*)u1p, 128);

  // 1) MFMA bf16x3 fused 2-layer GRU -> seq_emb (250 blocks x 640 thr, M=80)
  gru_mfma<<<250, 640, 0, stream>>>(x,
                                    (const unsigned short*)w0p, (const unsigned short*)u0p,
                                    (const unsigned short*)w1p, (const unsigned short*)u1p,
                                    bih0, bhh0, bih1, bhh1, seq);

  // 2) intra GAT: transform + CSR build + atomic-free gather
  gat_transform<<<313, 256, 0, stream>>>(seq, iW, ias, iad, hintra, es, ed, NCOMP);
  zero_i   <<<(NCOMP+255)/256, 256, 0, stream>>>(cnt, NCOMP);
  zero_i   <<<1, 256, 0, stream>>>(scnt, NSEC);
  csr_count<<<(EINTRA+255)/256, 256, 0, stream>>>(iei + EINTRA, cnt, EINTRA);
  csr_count<<<(NCOMP+255)/256, 256, 0, stream>>>(sid, scnt, NCOMP);
  csr_scan <<<1, 1024, 0, stream>>>(cnt, rowptr, cursor, NCOMP);
  csr_scan <<<1, 1024, 0, stream>>>(scnt, srowptr, scursor, NSEC);
  csr_fill <<<(EINTRA+255)/256, 256, 0, stream>>>(iei, iei + EINTRA, cursor, csrc, EINTRA);
  csr_fill <<<(NCOMP+255)/256, 256, 0, stream>>>(nullptr, sid, scursor, slist, NCOMP);
  gat_gather<<<NCOMP/4, 256, 0, stream>>>(rowptr, csrc, es, ed, hintra, ib, intra, NCOMP);

  // 3) per-sector max pool via sector row lists
  sector_pool<<<NSEC, 256, 0, stream>>>(intra, srowptr, slist, spool);

  // 4) inter GAT (tiny: 64 nodes, 4096 edges — atomic path)
  gat_init<<<32, 256, 0, stream>>>(mx2, den2, acc2, NSEC);
  gat_transform<<<1, 256, 0, stream>>>(spool, eW, eas, ead, hinter, es2, ed2, NSEC);
  {
    int tot = EINTER + NSEC;
    edge_max    <<<(tot+255)/256, 256, 0, stream>>>(eei, eei+EINTER, es2, ed2, mx2, EINTER, NSEC);
    edge_sum    <<<(tot+255)/256, 256, 0, stream>>>(eei, eei+EINTER, es2, ed2, mx2, den2, wbf2, EINTER, NSEC);
    edge_scatter<<<(tot*32)/256, 256, 0, stream>>>(eei, eei+EINTER, wbf2, den2, hinter, acc2, EINTER, NSEC);
  }
  inter_bias_k<<<32, 256, 0, stream>>>(acc2, eb, isec);

  // 5) fusion -> output [20000]
  fusion_k<<<NCOMP/4, 256, 0, stream>>>(seq, intra, isec, sid, fW, fb, (float*)d_out, NCOMP);
}

// Round 7
// 1855.557 us; speedup vs baseline: 4.2156x; 1.5867x over previous
//
#include <hip/hip_runtime.h>
#include <math.h>

// Problem constants
#define NCOMP 20000
#define SEQT  32
#define INSZ  64
#define HSZ   128
#define EINTRA 640000
#define EINTER 4096
#define NSEC  64

#define LDH 132   // padded LDS row stride (floats) for gat_transform

typedef __attribute__((ext_vector_type(8))) short bf16x8;   // 8 bf16 in 4 VGPRs
typedef __attribute__((ext_vector_type(4))) float f32x4;    // MFMA C/D frag

__device__ __forceinline__ float dot4f(float4 a, float4 b){
  return a.x*b.x + a.y*b.y + a.z*b.z + a.w*b.w;
}
__device__ __forceinline__ float sigm(float x){ return 1.f/(1.f + __expf(-x)); }
__device__ __forceinline__ float ftanh(float x){
  float cx = fminf(fmaxf(x, -15.f), 15.f);
  float e = __expf(2.f*cx);
  return (e - 1.f)/(e + 1.f);
}
// monotone float<->uint mapping so atomicMax works for signed floats (inter path)
__device__ __forceinline__ unsigned fordu(float f){
  unsigned b = __float_as_uint(f);
  return (b & 0x80000000u) ? ~b : (b | 0x80000000u);
}
__device__ __forceinline__ float unfordu(unsigned u){
  unsigned b = (u & 0x80000000u) ? (u & 0x7fffffffu) : ~u;
  return __uint_as_float(b);
}
#define NEG_MAX_ORD 0x00800000u   // fordu(-FLT_MAX)

// bf16 hi/lo split helpers (truncation split: w = hi + rem exactly, lo = bf16(rem))
__device__ __forceinline__ unsigned short bf16hi(float f){
  return (unsigned short)(__float_as_uint(f) >> 16);
}
__device__ __forceinline__ float bf16tof(unsigned short h){
  return __uint_as_float(((unsigned)h) << 16);
}

// ===========================================================================
// Weight packing for MFMA bf16x3: out[(kt*24+nt)*2+{hi,lo}][lane][8 bf16].
// Fragment convention (must match A-side): col n = lane&15 (within nt tile),
// k = kt*32 + (lane>>4)*8 + j.  One coalesced dwordx4 per fragment at use.
// (UNCHANGED from rounds 5/6 — layout verified correct by passing refchecks.)
// ===========================================================================
__global__ void wpack_mfma(const float* __restrict__ W, unsigned short* __restrict__ out, int K)
{
  int tid = blockIdx.x*256 + threadIdx.x;
  int KT = K >> 5;
  if (tid >= KT*24*64) return;
  int lane = tid & 63;
  int nt   = (tid >> 6) % 24;
  int kt   = (tid >> 6) / 24;
  int col  = nt*16 + (lane & 15);
  int kbase = kt*32 + (lane >> 4)*8;
  size_t b = ((size_t)(kt*24 + nt)*2*64 + lane)*8;   // hi at b, lo at b+512
  #pragma unroll
  for (int j = 0; j < 8; ++j){
    float w = W[(size_t)col*K + kbase + j];
    unsigned short h = bf16hi(w);
    float rem = w - bf16tof(h);
    out[b + j]       = h;
    out[b + 512 + j] = bf16hi(rem);
  }
}

// ===========================================================================
// MFMA bf16x3 fused 2-layer GRU, v3: M_rep=5 wave decomposition.
// Block = 512 thr (8 waves) = 80 companies (5 M-tiles), grid 250 (exact).
// Wave w owns dim-slice [16w, 16w+16) -> B-tiles {w, 8+w, 16+w} (R/Z/N).
// Round-6 diagnosis: wave=(mt,dh) made 5 waves re-load identical B frags
// (3.36 MB/t L1 traffic/CU, 2 loads per 9 MFMAs, both pipes <20% busy).
// Now each B frag is loaded by exactly ONE wave per CU (read-once, 672 KB/t)
// and amortized over 5 M-tiles of A held in registers: 6 loads per 45 MFMAs.
// hfr layout, pack layout, bf16x3 math, C/D map, 4 barriers/t: all identical
// to the verified round-6 kernel. Biases now live in 8 regs/thread (no LDS).
// ===========================================================================
__global__ __launch_bounds__(512, 2)
void gru_mfma(const float* __restrict__ x,
              const unsigned short* __restrict__ w0pk, const unsigned short* __restrict__ u0pk,
              const unsigned short* __restrict__ w1pk, const unsigned short* __restrict__ u1pk,
              const float* __restrict__ bih0, const float* __restrict__ bhh0,
              const float* __restrict__ bih1, const float* __restrict__ bhh1,
              float* __restrict__ seq)
{
  // [layer][hi/lo][kt][mtile][lane][8] : 2*2*4*5*64*8*2B = 80 KB
  __shared__ __align__(16) unsigned short hfr[2][2][4][5][64][8];

  const int tid = threadIdx.x;
  const int w = tid >> 6, l = tid & 63;
  const int cq = l & 15, kg = l >> 4;
  const int cbase = blockIdx.x*80;          // 250*80 == 20000 exactly, no tail
  const int d = w*16 + cq;                  // this thread's output dim [0,128)
  const int ktp = d >> 5, kgp = (d >> 3) & 3, jp = d & 7;  // h-frag cell for dim d

  // zero h state
  {
    float4 z4 = make_float4(0.f,0.f,0.f,0.f);
    float4* hz = (float4*)&hfr[0][0][0][0][0][0];
    for (int i = tid; i < 5120; i += 512) hz[i] = z4;   // 80 KB
  }
  // biases in registers (dim d fixed per thread)
  const float bR0 = bih0[d]       + bhh0[d];
  const float bZ0 = bih0[128 + d] + bhh0[128 + d];
  const float bX0 = bih0[256 + d];
  const float bH0 = bhh0[256 + d];
  const float bR1 = bih1[d]       + bhh1[d];
  const float bZ1 = bih1[128 + d] + bhh1[128 + d];
  const float bX1 = bih1[256 + d];
  const float bH1 = bhh1[256 + d];
  __syncthreads();

  f32x4 cR[5], cZ[5], cN[5], cH[5];

  #define CINIT(BR,BZ,BX,BH) do { \
    _Pragma("unroll") for (int mt = 0; mt < 5; ++mt){ \
      cR[mt] = (f32x4){BR,BR,BR,BR}; \
      cZ[mt] = (f32x4){BZ,BZ,BZ,BZ}; \
      cN[mt] = (f32x4){BX,BX,BX,BX}; \
      cH[mt] = (f32x4){BH,BH,BH,BH}; } \
  } while(0)

  #define MF3(AH, AL, BH, BL, C) do { \
    C = __builtin_amdgcn_mfma_f32_16x16x32_bf16(AH, BH, C, 0,0,0); \
    C = __builtin_amdgcn_mfma_f32_16x16x32_bf16(AH, BL, C, 0,0,0); \
    C = __builtin_amdgcn_mfma_f32_16x16x32_bf16(AL, BH, C, 0,0,0); \
  } while(0)

  // 3 B-tile-pairs (R/Z/C2 gates), each vs 5 A-tiles. _P already offset to kt.
  #define BGEMM(_P, AH, AL, C2) do { \
    { const bf16x8* bp = (const bf16x8*)((_P) + (size_t)w*1024); \
      bf16x8 bh = bp[0], bl = bp[64]; \
      _Pragma("unroll") for (int mt = 0; mt < 5; ++mt){ MF3(AH[mt], AL[mt], bh, bl, cR[mt]); } } \
    { const bf16x8* bp = (const bf16x8*)((_P) + (size_t)(8 + w)*1024); \
      bf16x8 bh = bp[0], bl = bp[64]; \
      _Pragma("unroll") for (int mt = 0; mt < 5; ++mt){ MF3(AH[mt], AL[mt], bh, bl, cZ[mt]); } } \
    { const bf16x8* bp = (const bf16x8*)((_P) + (size_t)(16 + w)*1024); \
      bf16x8 bh = bp[0], bl = bp[64]; \
      _Pragma("unroll") for (int mt = 0; mt < 5; ++mt){ MF3(AH[mt], AL[mt], bh, bl, C2[mt]); } } \
  } while(0)

  // one kt-slab with A = h fragments from LDS (2 conflict-free b128 per mt)
  #define GEMSLAB(PK, KT, LYR, C2) do { \
    const unsigned short* _p = (PK) + (size_t)(KT)*24576 + (size_t)l*8; \
    bf16x8 ah[5], al[5]; \
    _Pragma("unroll") for (int mt = 0; mt < 5; ++mt){ \
      ah[mt] = *(const bf16x8*)&hfr[LYR][0][KT][mt][l][0]; \
      al[mt] = *(const bf16x8*)&hfr[LYR][1][KT][mt][l][0]; } \
    BGEMM(_p, ah, al, C2); \
  } while(0)

  // one kt-slab with A = x from global (layer-0 input, K=64)
  #define GEMSLABX(KT) do { \
    const unsigned short* _p = w0pk + (size_t)(KT)*24576 + (size_t)l*8; \
    bf16x8 ah[5], al[5]; \
    _Pragma("unroll") for (int mt = 0; mt < 5; ++mt){ \
      const float* xp = x + ((size_t)(cbase + mt*16 + cq)*SEQT + t)*INSZ + (KT)*32 + kg*8; \
      float4 q0 = *(const float4*)xp; \
      float4 q1 = *(const float4*)(xp + 4); \
      float xf[8] = {q0.x,q0.y,q0.z,q0.w, q1.x,q1.y,q1.z,q1.w}; \
      _Pragma("unroll") for (int j = 0; j < 8; ++j){ \
        unsigned short h_ = bf16hi(xf[j]); \
        ah[mt][j] = (short)h_; \
        al[mt][j] = (short)bf16hi(xf[j] - bf16tof(h_)); } } \
    BGEMM(_p, ah, al, cN); \
  } while(0)

  // GRU elementwise for this thread's dim d across 5 mt x 4 comps.
  // C/D layout (m89-verified): col=cq (dim-in-tile), row=kg*4+r (comp).
  #define ELEM(LYR, DOSTORE) do { \
    _Pragma("unroll") for (int mt = 0; mt < 5; ++mt){ \
      unsigned short* hhi = &hfr[LYR][0][ktp][mt][0][0]; \
      unsigned short* hlo = &hfr[LYR][1][ktp][mt][0][0]; \
      _Pragma("unroll") for (int r = 0; r < 4; ++r){ \
        int lanep = kgp*16 + kg*4 + r; \
        float hold = bf16tof(hhi[lanep*8 + jp]) + bf16tof(hlo[lanep*8 + jp]); \
        float rr = sigm(cR[mt][r]); \
        float zz = sigm(cZ[mt][r]); \
        float nn = ftanh(cN[mt][r] + rr*cH[mt][r]); \
        float hn = (1.f - zz)*nn + zz*hold; \
        unsigned short hh = bf16hi(hn); \
        hhi[lanep*8 + jp] = hh; \
        hlo[lanep*8 + jp] = bf16hi(hn - bf16tof(hh)); \
        if (DOSTORE) seq[(size_t)(cbase + mt*16 + kg*4 + r)*HSZ + d] = hn; } } \
  } while(0)

  #pragma unroll 1
  for (int t = 0; t < SEQT; ++t){
    // ================= layer 0 =================
    CINIT(bR0, bZ0, bX0, bH0);
    GEMSLABX(0);                       // x part, K=64
    GEMSLABX(1);
    GEMSLAB(u0pk, 0, 0, cH);           // h part, K=128 (A = h0_old)
    GEMSLAB(u0pk, 1, 0, cH);
    GEMSLAB(u0pk, 2, 0, cH);
    GEMSLAB(u0pk, 3, 0, cH);
    __syncthreads();                   // all waves done reading h0_old
    ELEM(0, false);
    __syncthreads();                   // h0_new visible
    // ================= layer 1 =================
    CINIT(bR1, bZ1, bX1, bH1);
    GEMSLAB(w1pk, 0, 0, cN);           // input = h0_new
    GEMSLAB(w1pk, 1, 0, cN);
    GEMSLAB(w1pk, 2, 0, cN);
    GEMSLAB(w1pk, 3, 0, cN);
    GEMSLAB(u1pk, 0, 1, cH);           // hidden h1_old
    GEMSLAB(u1pk, 1, 1, cH);
    GEMSLAB(u1pk, 2, 1, cH);
    GEMSLAB(u1pk, 3, 1, cH);
    __syncthreads();                   // all waves done reading h1_old
    ELEM(1, (t == SEQT-1));
    __syncthreads();                   // h1_new visible for next t
  }
  #undef CINIT
  #undef MF3
  #undef BGEMM
  #undef GEMSLAB
  #undef GEMSLABX
  #undef ELEM
}

// ===========================================================================
// GAT stage — CSR build + atomic-free per-node gather
// ===========================================================================
__global__ __launch_bounds__(256)
void gat_transform(const float* __restrict__ X, const float* __restrict__ W,
                   const float* __restrict__ asrc, const float* __restrict__ adst,
                   float* __restrict__ Hout, float* __restrict__ es, float* __restrict__ ed,
                   int n)
{
  __shared__ float sX[64*LDH];
  const int tid = threadIdx.x;
  const long base = (long)blockIdx.x * 64;
  for (int i = tid; i < 64*32; i += 256){
    int row = i >> 5, q = i & 31;
    long gr = base + row;
    float4 v = make_float4(0.f, 0.f, 0.f, 0.f);
    if (gr < n) v = ((const float4*)(X + gr*HSZ))[q];
    ((float4*)(sX + row*LDH))[q] = v;
  }
  __syncthreads();
  const int rp = tid >> 3, dg = tid & 7;
  const int r0 = rp*2, r1 = r0 + 1;
  const float4* xa = (const float4*)(sX + r0*LDH);
  const float4* xb = (const float4*)(sX + r1*LDH);
  float ps0=0.f, pd0=0.f, ps1=0.f, pd1=0.f;
  for (int dd = 0; dd < 16; ++dd){
    const int cidx = dg*16 + dd;
    const float4* wp = (const float4*)(W + cidx*HSZ);
    float a0 = 0.f, a1 = 0.f;
    #pragma unroll 4
    for (int q = 0; q < 32; ++q){
      float4 w = wp[q];
      a0 += dot4f(w, xa[q]);
      a1 += dot4f(w, xb[q]);
    }
    float s = asrc[cidx], dv = adst[cidx];
    ps0 += a0*s; pd0 += a0*dv;
    ps1 += a1*s; pd1 += a1*dv;
    if (base + r0 < n) Hout[(base+r0)*HSZ + cidx] = a0;
    if (base + r1 < n) Hout[(base+r1)*HSZ + cidx] = a1;
  }
  #pragma unroll
  for (int m = 1; m < 8; m <<= 1){
    ps0 += __shfl_xor(ps0, m, 64);
    pd0 += __shfl_xor(pd0, m, 64);
    ps1 += __shfl_xor(ps1, m, 64);
    pd1 += __shfl_xor(pd1, m, 64);
  }
  if (dg == 0){
    if (base + r0 < n){ es[base+r0] = ps0; ed[base+r0] = pd0; }
    if (base + r1 < n){ es[base+r1] = ps1; ed[base+r1] = pd1; }
  }
}

__global__ void zero_i(int* __restrict__ p, int n)
{
  int i = blockIdx.x*256 + threadIdx.x;
  if (i < n) p[i] = 0;
}

__global__ void csr_count(const int* __restrict__ key, int* __restrict__ cnt, int E)
{
  int i = blockIdx.x*256 + threadIdx.x;
  if (i < E) atomicAdd(&cnt[key[i]], 1);
}

// single block, 1024 threads: exclusive scan of cnt[0..n) -> rowptr, cursor
__global__ __launch_bounds__(1024)
void csr_scan(const int* __restrict__ cnt, int* __restrict__ rowptr,
              int* __restrict__ cursor, int n)
{
  __shared__ int ls[1024];
  const int t = threadIdx.x;
  const int base = t*20;
  int loc[20];
  int s = 0;
  #pragma unroll
  for (int k = 0; k < 20; ++k){
    int idx = base + k;
    int v = (idx < n) ? cnt[idx] : 0;
    loc[k] = s; s += v;
  }
  ls[t] = s;
  __syncthreads();
  for (int off = 1; off < 1024; off <<= 1){
    int v = (t >= off) ? ls[t-off] : 0;
    __syncthreads();
    ls[t] += v;
    __syncthreads();
  }
  int excl = (t == 0) ? 0 : ls[t-1];
  #pragma unroll
  for (int k = 0; k < 20; ++k){
    int idx = base + k;
    if (idx < n){ int rp = excl + loc[k]; rowptr[idx] = rp; cursor[idx] = rp; }
  }
  if (t == 1023) rowptr[n] = ls[1023];
}

// val==nullptr -> store the element index i (used for sector row lists)
__global__ void csr_fill(const int* __restrict__ val, const int* __restrict__ key,
                         int* __restrict__ cursor, int* __restrict__ outl, int E)
{
  int i = blockIdx.x*256 + threadIdx.x;
  if (i >= E) return;
  int p = atomicAdd(&cursor[key[i]], 1);
  outl[p] = val ? val[i] : i;
}

// one wave per destination node: leaky-relu logits, max, denom, weighted gather
__global__ __launch_bounds__(256)
void gat_gather(const int* __restrict__ rowptr, const int* __restrict__ csrc,
                const float* __restrict__ es, const float* __restrict__ ed,
                const float* __restrict__ Hv, const float* __restrict__ bias,
                float* __restrict__ out, int n)
{
  int d = blockIdx.x*4 + (threadIdx.x >> 6);
  int l = threadIdx.x & 63;
  if (d >= n) return;
  const int p0 = rowptr[d], p1 = rowptr[d+1];
  const float edd = ed[d];
  float eself = es[d] + edd;
  eself = eself > 0.f ? eself : 0.2f*eself;
  float m = eself;
  for (int j = p0 + l; j < p1; j += 64){
    int s = csrc[j];
    float e = es[s] + edd;
    e = e > 0.f ? e : 0.2f*e;
    m = fmaxf(m, e);
  }
  #pragma unroll
  for (int off = 1; off < 64; off <<= 1) m = fmaxf(m, __shfl_xor(m, off, 64));
  float part = 0.f;
  for (int j = p0 + l; j < p1; j += 64){
    int s = csrc[j];
    float e = es[s] + edd;
    e = e > 0.f ? e : 0.2f*e;
    part += __expf(e - m);
  }
  #pragma unroll
  for (int off = 1; off < 64; off <<= 1) part += __shfl_xor(part, off, 64);
  const float wself = __expf(eself - m);
  const float inv = 1.f/(part + wself);
  float a = wself*inv;
  float acc0 = a * Hv[(long)d*HSZ + l];
  float acc1 = a * Hv[(long)d*HSZ + 64 + l];
  for (int j = p0; j < p1; ++j){
    int s = csrc[j];
    float e = es[s] + edd;
    e = e > 0.f ? e : 0.2f*e;
    float al = __expf(e - m)*inv;
    acc0 += al * Hv[(long)s*HSZ + l];
    acc1 += al * Hv[(long)s*HSZ + 64 + l];
  }
  out[(long)d*HSZ + l]      = acc0 + bias[l];
  out[(long)d*HSZ + 64 + l] = acc1 + bias[64 + l];
}

// per-sector max pool using sector row-list (CSR over sid)
__global__ __launch_bounds__(256)
void sector_pool(const float* __restrict__ intra, const int* __restrict__ srowptr,
                 const int* __restrict__ slist, float* __restrict__ spool)
{
  const int sec = blockIdx.x;
  const int t = threadIdx.x;
  const int d = t & 127, half = t >> 7;
  const int p0 = srowptr[sec], p1 = srowptr[sec+1];
  float m = -3.402823466e+38f;
  for (int j = p0 + half; j < p1; j += 2){
    int r = slist[j];
    m = fmaxf(m, intra[(long)r*HSZ + d]);
  }
  __shared__ float red[256];
  red[t] = m;
  __syncthreads();
  if (half == 0) spool[sec*HSZ + d] = fmaxf(red[d], red[128 + d]);
}

// ---- inter-sector GAT (tiny, keep atomic path) ----
__global__ void gat_init(unsigned* __restrict__ maxb, float* __restrict__ den,
                         float* __restrict__ acc, int n)
{
  long i = (long)blockIdx.x*256 + threadIdx.x;
  if (i < n){ maxb[i] = NEG_MAX_ORD; den[i] = 0.f; }
  if (i < (long)n*HSZ) acc[i] = 0.f;
}

__global__ void edge_max(const int* __restrict__ src, const int* __restrict__ dst,
                         const float* __restrict__ es, const float* __restrict__ ed,
                         unsigned* __restrict__ maxb, int E, int n)
{
  int i = blockIdx.x*256 + threadIdx.x;
  if (i >= E + n) return;
  int s, d;
  if (i < E){ s = src[i]; d = dst[i]; } else { s = d = i - E; }
  float e = es[s] + ed[d];
  e = e > 0.f ? e : 0.2f*e;
  atomicMax(maxb + d, fordu(e));
}

__global__ void edge_sum(const int* __restrict__ src, const int* __restrict__ dst,
                         const float* __restrict__ es, const float* __restrict__ ed,
                         const unsigned* __restrict__ maxb, float* __restrict__ den,
                         float* __restrict__ wbuf, int E, int n)
{
  int i = blockIdx.x*256 + threadIdx.x;
  if (i >= E + n) return;
  int s, d;
  if (i < E){ s = src[i]; d = dst[i]; } else { s = d = i - E; }
  float e = es[s] + ed[d];
  e = e > 0.f ? e : 0.2f*e;
  float w = __expf(e - unfordu(maxb[d]));
  wbuf[i] = w;
  atomicAdd(den + d, w);
}

__global__ void edge_scatter(const int* __restrict__ src, const int* __restrict__ dst,
                             const float* __restrict__ wbuf, const float* __restrict__ den,
                             const float* __restrict__ Hv, float* __restrict__ acc,
                             int E, int n)
{
  long t = (long)blockIdx.x*256 + threadIdx.x;
  long i = t >> 5;
  int  j = (int)(t & 31);
  if (i >= E + n) return;
  int s, d;
  if (i < E){ s = src[i]; d = dst[i]; } else { s = d = (int)(i - E); }
  float alpha = wbuf[i] / den[d];
  float4 hv = ((const float4*)(Hv + (long)s*HSZ))[j];
  float* o = acc + (long)d*HSZ + j*4;
  atomicAdd(o+0, alpha*hv.x);
  atomicAdd(o+1, alpha*hv.y);
  atomicAdd(o+2, alpha*hv.z);
  atomicAdd(o+3, alpha*hv.w);
}

__global__ void inter_bias_k(const float* __restrict__ acc2, const float* __restrict__ bias,
                             float* __restrict__ isec)
{
  int i = blockIdx.x*256 + threadIdx.x;   // exactly 64*128
  isec[i] = acc2[i] + bias[i & 127];
}

__global__ __launch_bounds__(256)
void fusion_k(const float* __restrict__ seq, const float* __restrict__ intra,
              const float* __restrict__ isec, const int* __restrict__ sid,
              const float* __restrict__ fw, const float* __restrict__ fb,
              float* __restrict__ out, int n)
{
  int i = blockIdx.x*4 + (threadIdx.x >> 6);
  int l = threadIdx.x & 63;
  if (i >= n) return;
  int sc = sid[i];
  long b = (long)i*HSZ;
  long sb = (long)sc*HSZ;
  float acc = fw[l]     * seq[b + l]      + fw[64 + l]  * seq[b + 64 + l]
            + fw[128+l] * intra[b + l]    + fw[192 + l] * intra[b + 64 + l]
            + fw[256+l] * isec[sb + l]    + fw[320 + l] * isec[sb + 64 + l];
  #pragma unroll
  for (int m = 1; m < 64; m <<= 1) acc += __shfl_xor(acc, m, 64);
  if (l == 0) out[i] = acc + fb[0];
}

extern "C" void kernel_launch(void* const* d_in, const int* in_sizes, int n_in,
                              void* d_out, int out_size, void* d_ws, size_t ws_size,
                              hipStream_t stream)
{
  const float* x    = (const float*)d_in[0];
  const int*   iei  = (const int*)d_in[1];    // [2, 640000]
  const int*   eei  = (const int*)d_in[2];    // [2, 4096]
  const int*   sid  = (const int*)d_in[3];
  const float* wih0 = (const float*)d_in[4];
  const float* whh0 = (const float*)d_in[5];
  const float* bih0 = (const float*)d_in[6];
  const float* bhh0 = (const float*)d_in[7];
  const float* wih1 = (const float*)d_in[8];
  const float* whh1 = (const float*)d_in[9];
  const float* bih1 = (const float*)d_in[10];
  const float* bhh1 = (const float*)d_in[11];
  const float* iW   = (const float*)d_in[12];
  const float* ias  = (const float*)d_in[13];
  const float* iad  = (const float*)d_in[14];
  const float* ib   = (const float*)d_in[15];
  const float* eW   = (const float*)d_in[16];
  const float* eas  = (const float*)d_in[17];
  const float* ead  = (const float*)d_in[18];
  const float* eb   = (const float*)d_in[19];
  const float* fW   = (const float*)d_in[20];
  const float* fb   = (const float*)d_in[21];

  float* ws = (float*)d_ws;
  long off = 0;
  float* seq    = ws + off; off += 2560000;
  float* hintra = ws + off; off += 2560000;
  float* intra  = ws + off; off += 2560000;
  float* es     = ws + off; off += 20000;
  float* ed     = ws + off; off += 20000;
  int*   cnt    = (int*)(ws + off); off += 20000;
  int*   rowptr = (int*)(ws + off); off += 20004;
  int*   cursor = (int*)(ws + off); off += 20000;
  int*   csrc   = (int*)(ws + off); off += 640000;
  int*   scnt    = (int*)(ws + off); off += 64;
  int*   srowptr = (int*)(ws + off); off += 68;
  int*   scursor = (int*)(ws + off); off += 64;
  int*   slist   = (int*)(ws + off); off += 20000;
  float* w0p = ws + off; off += 24576;   // bf16x3 pack: 2kt*24nt*2*1024B
  float* u0p = ws + off; off += 49152;   // 4kt
  float* w1p = ws + off; off += 49152;
  float* u1p = ws + off; off += 49152;
  float* spool  = ws + off; off += 8192;
  float* hinter = ws + off; off += 8192;
  float* acc2   = ws + off; off += 8192;
  float* es2    = ws + off; off += 64;
  float* ed2    = ws + off; off += 64;
  unsigned* mx2 = (unsigned*)(ws + off); off += 64;
  float* den2   = ws + off; off += 64;
  float* wbf2   = ws + off; off += 4160;
  float* isec   = ws + off; off += 8192;
  // total ~8.6M floats = ~34.5 MB

  // 0) pack GRU weights into bf16 hi/lo MFMA fragment layout
  wpack_mfma<<<12, 256, 0, stream>>>(wih0, (unsigned short*)w0p, 64);
  wpack_mfma<<<24, 256, 0, stream>>>(whh0, (unsigned short*)u0p, 128);
  wpack_mfma<<<24, 256, 0, stream>>>(wih1, (unsigned short*)w1p, 128);
  wpack_mfma<<<24, 256, 0, stream>>>(whh1, (unsigned short*)u1p, 128);

  // 1) MFMA bf16x3 fused 2-layer GRU -> seq_emb (250 blocks x 512 thr, M=80)
  gru_mfma<<<250, 512, 0, stream>>>(x,
                                    (const unsigned short*)w0p, (const unsigned short*)u0p,
                                    (const unsigned short*)w1p, (const unsigned short*)u1p,
                                    bih0, bhh0, bih1, bhh1, seq);

  // 2) intra GAT: transform + CSR build + atomic-free gather
  gat_transform<<<313, 256, 0, stream>>>(seq, iW, ias, iad, hintra, es, ed, NCOMP);
  zero_i   <<<(NCOMP+255)/256, 256, 0, stream>>>(cnt, NCOMP);
  zero_i   <<<1, 256, 0, stream>>>(scnt, NSEC);
  csr_count<<<(EINTRA+255)/256, 256, 0, stream>>>(iei + EINTRA, cnt, EINTRA);
  csr_count<<<(NCOMP+255)/256, 256, 0, stream>>>(sid, scnt, NCOMP);
  csr_scan <<<1, 1024, 0, stream>>>(cnt, rowptr, cursor, NCOMP);
  csr_scan <<<1, 1024, 0, stream>>>(scnt, srowptr, scursor, NSEC);
  csr_fill <<<(EINTRA+255)/256, 256, 0, stream>>>(iei, iei + EINTRA, cursor, csrc, EINTRA);
  csr_fill <<<(NCOMP+255)/256, 256, 0, stream>>>(nullptr, sid, scursor, slist, NCOMP);
  gat_gather<<<NCOMP/4, 256, 0, stream>>>(rowptr, csrc, es, ed, hintra, ib, intra, NCOMP);

  // 3) per-sector max pool via sector row lists
  sector_pool<<<NSEC, 256, 0, stream>>>(intra, srowptr, slist, spool);

  // 4) inter GAT (tiny: 64 nodes, 4096 edges — atomic path)
  gat_init<<<32, 256, 0, stream>>>(mx2, den2, acc2, NSEC);
  gat_transform<<<1, 256, 0, stream>>>(spool, eW, eas, ead, hinter, es2, ed2, NSEC);
  {
    int tot = EINTER + NSEC;
    edge_max    <<<(tot+255)/256, 256, 0, stream>>>(eei, eei+EINTER, es2, ed2, mx2, EINTER, NSEC);
    edge_sum    <<<(tot+255)/256, 256, 0, stream>>>(eei, eei+EINTER, es2, ed2, mx2, den2, wbf2, EINTER, NSEC);
    edge_scatter<<<(tot*32)/256, 256, 0, stream>>>(eei, eei+EINTER, wbf2, den2, hinter, acc2, EINTER, NSEC);
  }
  inter_bias_k<<<32, 256, 0, stream>>>(acc2, eb, isec);

  // 5) fusion -> output [20000]
  fusion_k<<<NCOMP/4, 256, 0, stream>>>(seq, intra, isec, sid, fW, fb, (float*)d_out, NCOMP);
}

// Round 8
// 1847.292 us; speedup vs baseline: 4.2345x; 1.0045x over previous
//
#include <hip/hip_runtime.h>
#include <math.h>

// Problem constants
#define NCOMP 20000
#define SEQT  32
#define INSZ  64
#define HSZ   128
#define EINTRA 640000
#define EINTER 4096
#define NSEC  64

#define LDH 132   // padded LDS row stride (floats) for gat_transform

typedef __attribute__((ext_vector_type(8))) short bf16x8;   // 8 bf16 in 4 VGPRs
typedef __attribute__((ext_vector_type(4))) float f32x4;    // MFMA C/D frag

__device__ __forceinline__ float dot4f(float4 a, float4 b){
  return a.x*b.x + a.y*b.y + a.z*b.z + a.w*b.w;
}
__device__ __forceinline__ float sigm(float x){ return 1.f/(1.f + __expf(-x)); }
__device__ __forceinline__ float ftanh(float x){
  float cx = fminf(fmaxf(x, -15.f), 15.f);
  float e = __expf(2.f*cx);
  return (e - 1.f)/(e + 1.f);
}
// monotone float<->uint mapping so atomicMax works for signed floats (inter path)
__device__ __forceinline__ unsigned fordu(float f){
  unsigned b = __float_as_uint(f);
  return (b & 0x80000000u) ? ~b : (b | 0x80000000u);
}
__device__ __forceinline__ float unfordu(unsigned u){
  unsigned b = (u & 0x80000000u) ? (u & 0x7fffffffu) : ~u;
  return __uint_as_float(b);
}
#define NEG_MAX_ORD 0x00800000u   // fordu(-FLT_MAX)

// bf16 hi/lo split helpers (truncation split: w = hi + rem exactly, lo = bf16(rem))
__device__ __forceinline__ unsigned short bf16hi(float f){
  return (unsigned short)(__float_as_uint(f) >> 16);
}
__device__ __forceinline__ float bf16tof(unsigned short h){
  return __uint_as_float(((unsigned)h) << 16);
}

// ===========================================================================
// Weight packing for MFMA bf16x3: out[(kt*24+nt)*2+{hi,lo}][lane][8 bf16].
// Fragment convention (must match A-side): col n = lane&15 (within nt tile),
// k = kt*32 + (lane>>4)*8 + j.  One coalesced dwordx4 per fragment at use.
// (UNCHANGED from rounds 5-7 — layout verified correct by passing refchecks.)
// ===========================================================================
__global__ void wpack_mfma(const float* __restrict__ W, unsigned short* __restrict__ out, int K)
{
  int tid = blockIdx.x*256 + threadIdx.x;
  int KT = K >> 5;
  if (tid >= KT*24*64) return;
  int lane = tid & 63;
  int nt   = (tid >> 6) % 24;
  int kt   = (tid >> 6) / 24;
  int col  = nt*16 + (lane & 15);
  int kbase = kt*32 + (lane >> 4)*8;
  size_t b = ((size_t)(kt*24 + nt)*2*64 + lane)*8;   // hi at b, lo at b+512
  #pragma unroll
  for (int j = 0; j < 8; ++j){
    float w = W[(size_t)col*K + kbase + j];
    unsigned short h = bf16hi(w);
    float rem = w - bf16tof(h);
    out[b + j]       = h;
    out[b + 512 + j] = bf16hi(rem);
  }
}

// ===========================================================================
// MFMA bf16x3 fused 2-layer GRU, v3.1: M_rep=5 wave decomposition, no spill.
// Block = 512 thr (8 waves) = 80 companies (5 M-tiles), grid 250 (exact).
// Wave w owns dim-slice [16w, 16w+16) -> B-tiles {w, 8+w, 16+w} (R/Z/N);
// each B frag loaded by exactly ONE wave per CU, amortized over 5 A-tiles.
// ROUND-7 FIX: launch_bounds (512,2) capped VGPR at 128 -> ~223MB/dispatch
// scratch spill (WRITE_SIZE 233MB vs 10MB seq). Grid=250 < 256 CUs means
// only 1 block/CU ever resides, so the min-2 declaration bought nothing.
// (512,1) -> 256-VGPR cap; kernel wants ~200 (C 80 + A 40 + B 8 + addr);
// same 8 waves/CU residency, zero spill.
// hfr layout, pack layout, bf16x3 math, C/D map, 4 barriers/t: unchanged.
// ===========================================================================
__global__ __launch_bounds__(512, 1)
void gru_mfma(const float* __restrict__ x,
              const unsigned short* __restrict__ w0pk, const unsigned short* __restrict__ u0pk,
              const unsigned short* __restrict__ w1pk, const unsigned short* __restrict__ u1pk,
              const float* __restrict__ bih0, const float* __restrict__ bhh0,
              const float* __restrict__ bih1, const float* __restrict__ bhh1,
              float* __restrict__ seq)
{
  // [layer][hi/lo][kt][mtile][lane][8] : 2*2*4*5*64*8*2B = 80 KB
  __shared__ __align__(16) unsigned short hfr[2][2][4][5][64][8];

  const int tid = threadIdx.x;
  const int w = tid >> 6, l = tid & 63;
  const int cq = l & 15, kg = l >> 4;
  const int cbase = blockIdx.x*80;          // 250*80 == 20000 exactly, no tail
  const int d = w*16 + cq;                  // this thread's output dim [0,128)
  const int ktp = d >> 5, kgp = (d >> 3) & 3, jp = d & 7;  // h-frag cell for dim d

  // zero h state
  {
    float4 z4 = make_float4(0.f,0.f,0.f,0.f);
    float4* hz = (float4*)&hfr[0][0][0][0][0][0];
    for (int i = tid; i < 5120; i += 512) hz[i] = z4;   // 80 KB
  }
  // biases in registers (dim d fixed per thread)
  const float bR0 = bih0[d]       + bhh0[d];
  const float bZ0 = bih0[128 + d] + bhh0[128 + d];
  const float bX0 = bih0[256 + d];
  const float bH0 = bhh0[256 + d];
  const float bR1 = bih1[d]       + bhh1[d];
  const float bZ1 = bih1[128 + d] + bhh1[128 + d];
  const float bX1 = bih1[256 + d];
  const float bH1 = bhh1[256 + d];
  __syncthreads();

  f32x4 cR[5], cZ[5], cN[5], cH[5];

  #define CINIT(BR,BZ,BX,BH) do { \
    _Pragma("unroll") for (int mt = 0; mt < 5; ++mt){ \
      cR[mt] = (f32x4){BR,BR,BR,BR}; \
      cZ[mt] = (f32x4){BZ,BZ,BZ,BZ}; \
      cN[mt] = (f32x4){BX,BX,BX,BX}; \
      cH[mt] = (f32x4){BH,BH,BH,BH}; } \
  } while(0)

  #define MF3(AH, AL, BH, BL, C) do { \
    C = __builtin_amdgcn_mfma_f32_16x16x32_bf16(AH, BH, C, 0,0,0); \
    C = __builtin_amdgcn_mfma_f32_16x16x32_bf16(AH, BL, C, 0,0,0); \
    C = __builtin_amdgcn_mfma_f32_16x16x32_bf16(AL, BH, C, 0,0,0); \
  } while(0)

  // 3 B-tile-pairs (R/Z/C2 gates), each vs 5 A-tiles. _P already offset to kt.
  #define BGEMM(_P, AH, AL, C2) do { \
    { const bf16x8* bp = (const bf16x8*)((_P) + (size_t)w*1024); \
      bf16x8 bh = bp[0], bl = bp[64]; \
      _Pragma("unroll") for (int mt = 0; mt < 5; ++mt){ MF3(AH[mt], AL[mt], bh, bl, cR[mt]); } } \
    { const bf16x8* bp = (const bf16x8*)((_P) + (size_t)(8 + w)*1024); \
      bf16x8 bh = bp[0], bl = bp[64]; \
      _Pragma("unroll") for (int mt = 0; mt < 5; ++mt){ MF3(AH[mt], AL[mt], bh, bl, cZ[mt]); } } \
    { const bf16x8* bp = (const bf16x8*)((_P) + (size_t)(16 + w)*1024); \
      bf16x8 bh = bp[0], bl = bp[64]; \
      _Pragma("unroll") for (int mt = 0; mt < 5; ++mt){ MF3(AH[mt], AL[mt], bh, bl, C2[mt]); } } \
  } while(0)

  // one kt-slab with A = h fragments from LDS (2 conflict-free b128 per mt)
  #define GEMSLAB(PK, KT, LYR, C2) do { \
    const unsigned short* _p = (PK) + (size_t)(KT)*24576 + (size_t)l*8; \
    bf16x8 ah[5], al[5]; \
    _Pragma("unroll") for (int mt = 0; mt < 5; ++mt){ \
      ah[mt] = *(const bf16x8*)&hfr[LYR][0][KT][mt][l][0]; \
      al[mt] = *(const bf16x8*)&hfr[LYR][1][KT][mt][l][0]; } \
    BGEMM(_p, ah, al, C2); \
  } while(0)

  // one kt-slab with A = x from global (layer-0 input, K=64)
  #define GEMSLABX(KT) do { \
    const unsigned short* _p = w0pk + (size_t)(KT)*24576 + (size_t)l*8; \
    bf16x8 ah[5], al[5]; \
    _Pragma("unroll") for (int mt = 0; mt < 5; ++mt){ \
      const float* xp = x + ((size_t)(cbase + mt*16 + cq)*SEQT + t)*INSZ + (KT)*32 + kg*8; \
      float4 q0 = *(const float4*)xp; \
      float4 q1 = *(const float4*)(xp + 4); \
      float xf[8] = {q0.x,q0.y,q0.z,q0.w, q1.x,q1.y,q1.z,q1.w}; \
      _Pragma("unroll") for (int j = 0; j < 8; ++j){ \
        unsigned short h_ = bf16hi(xf[j]); \
        ah[mt][j] = (short)h_; \
        al[mt][j] = (short)bf16hi(xf[j] - bf16tof(h_)); } } \
    BGEMM(_p, ah, al, cN); \
  } while(0)

  // GRU elementwise for this thread's dim d across 5 mt x 4 comps.
  // C/D layout (m89-verified): col=cq (dim-in-tile), row=kg*4+r (comp).
  #define ELEM(LYR, DOSTORE) do { \
    _Pragma("unroll") for (int mt = 0; mt < 5; ++mt){ \
      unsigned short* hhi = &hfr[LYR][0][ktp][mt][0][0]; \
      unsigned short* hlo = &hfr[LYR][1][ktp][mt][0][0]; \
      _Pragma("unroll") for (int r = 0; r < 4; ++r){ \
        int lanep = kgp*16 + kg*4 + r; \
        float hold = bf16tof(hhi[lanep*8 + jp]) + bf16tof(hlo[lanep*8 + jp]); \
        float rr = sigm(cR[mt][r]); \
        float zz = sigm(cZ[mt][r]); \
        float nn = ftanh(cN[mt][r] + rr*cH[mt][r]); \
        float hn = (1.f - zz)*nn + zz*hold; \
        unsigned short hh = bf16hi(hn); \
        hhi[lanep*8 + jp] = hh; \
        hlo[lanep*8 + jp] = bf16hi(hn - bf16tof(hh)); \
        if (DOSTORE) seq[(size_t)(cbase + mt*16 + kg*4 + r)*HSZ + d] = hn; } } \
  } while(0)

  #pragma unroll 1
  for (int t = 0; t < SEQT; ++t){
    // ================= layer 0 =================
    CINIT(bR0, bZ0, bX0, bH0);
    GEMSLABX(0);                       // x part, K=64
    GEMSLABX(1);
    GEMSLAB(u0pk, 0, 0, cH);           // h part, K=128 (A = h0_old)
    GEMSLAB(u0pk, 1, 0, cH);
    GEMSLAB(u0pk, 2, 0, cH);
    GEMSLAB(u0pk, 3, 0, cH);
    __syncthreads();                   // all waves done reading h0_old
    ELEM(0, false);
    __syncthreads();                   // h0_new visible
    // ================= layer 1 =================
    CINIT(bR1, bZ1, bX1, bH1);
    GEMSLAB(w1pk, 0, 0, cN);           // input = h0_new
    GEMSLAB(w1pk, 1, 0, cN);
    GEMSLAB(w1pk, 2, 0, cN);
    GEMSLAB(w1pk, 3, 0, cN);
    GEMSLAB(u1pk, 0, 1, cH);           // hidden h1_old
    GEMSLAB(u1pk, 1, 1, cH);
    GEMSLAB(u1pk, 2, 1, cH);
    GEMSLAB(u1pk, 3, 1, cH);
    __syncthreads();                   // all waves done reading h1_old
    ELEM(1, (t == SEQT-1));
    __syncthreads();                   // h1_new visible for next t
  }
  #undef CINIT
  #undef MF3
  #undef BGEMM
  #undef GEMSLAB
  #undef GEMSLABX
  #undef ELEM
}

// ===========================================================================
// GAT stage — CSR build + atomic-free per-node gather
// ===========================================================================
__global__ __launch_bounds__(256)
void gat_transform(const float* __restrict__ X, const float* __restrict__ W,
                   const float* __restrict__ asrc, const float* __restrict__ adst,
                   float* __restrict__ Hout, float* __restrict__ es, float* __restrict__ ed,
                   int n)
{
  __shared__ float sX[64*LDH];
  const int tid = threadIdx.x;
  const long base = (long)blockIdx.x * 64;
  for (int i = tid; i < 64*32; i += 256){
    int row = i >> 5, q = i & 31;
    long gr = base + row;
    float4 v = make_float4(0.f, 0.f, 0.f, 0.f);
    if (gr < n) v = ((const float4*)(X + gr*HSZ))[q];
    ((float4*)(sX + row*LDH))[q] = v;
  }
  __syncthreads();
  const int rp = tid >> 3, dg = tid & 7;
  const int r0 = rp*2, r1 = r0 + 1;
  const float4* xa = (const float4*)(sX + r0*LDH);
  const float4* xb = (const float4*)(sX + r1*LDH);
  float ps0=0.f, pd0=0.f, ps1=0.f, pd1=0.f;
  for (int dd = 0; dd < 16; ++dd){
    const int cidx = dg*16 + dd;
    const float4* wp = (const float4*)(W + cidx*HSZ);
    float a0 = 0.f, a1 = 0.f;
    #pragma unroll 4
    for (int q = 0; q < 32; ++q){
      float4 w = wp[q];
      a0 += dot4f(w, xa[q]);
      a1 += dot4f(w, xb[q]);
    }
    float s = asrc[cidx], dv = adst[cidx];
    ps0 += a0*s; pd0 += a0*dv;
    ps1 += a1*s; pd1 += a1*dv;
    if (base + r0 < n) Hout[(base+r0)*HSZ + cidx] = a0;
    if (base + r1 < n) Hout[(base+r1)*HSZ + cidx] = a1;
  }
  #pragma unroll
  for (int m = 1; m < 8; m <<= 1){
    ps0 += __shfl_xor(ps0, m, 64);
    pd0 += __shfl_xor(pd0, m, 64);
    ps1 += __shfl_xor(ps1, m, 64);
    pd1 += __shfl_xor(pd1, m, 64);
  }
  if (dg == 0){
    if (base + r0 < n){ es[base+r0] = ps0; ed[base+r0] = pd0; }
    if (base + r1 < n){ es[base+r1] = ps1; ed[base+r1] = pd1; }
  }
}

__global__ void zero_i(int* __restrict__ p, int n)
{
  int i = blockIdx.x*256 + threadIdx.x;
  if (i < n) p[i] = 0;
}

__global__ void csr_count(const int* __restrict__ key, int* __restrict__ cnt, int E)
{
  int i = blockIdx.x*256 + threadIdx.x;
  if (i < E) atomicAdd(&cnt[key[i]], 1);
}

// single block, 1024 threads: exclusive scan of cnt[0..n) -> rowptr, cursor
__global__ __launch_bounds__(1024)
void csr_scan(const int* __restrict__ cnt, int* __restrict__ rowptr,
              int* __restrict__ cursor, int n)
{
  __shared__ int ls[1024];
  const int t = threadIdx.x;
  const int base = t*20;
  int loc[20];
  int s = 0;
  #pragma unroll
  for (int k = 0; k < 20; ++k){
    int idx = base + k;
    int v = (idx < n) ? cnt[idx] : 0;
    loc[k] = s; s += v;
  }
  ls[t] = s;
  __syncthreads();
  for (int off = 1; off < 1024; off <<= 1){
    int v = (t >= off) ? ls[t-off] : 0;
    __syncthreads();
    ls[t] += v;
    __syncthreads();
  }
  int excl = (t == 0) ? 0 : ls[t-1];
  #pragma unroll
  for (int k = 0; k < 20; ++k){
    int idx = base + k;
    if (idx < n){ int rp = excl + loc[k]; rowptr[idx] = rp; cursor[idx] = rp; }
  }
  if (t == 1023) rowptr[n] = ls[1023];
}

// val==nullptr -> store the element index i (used for sector row lists)
__global__ void csr_fill(const int* __restrict__ val, const int* __restrict__ key,
                         int* __restrict__ cursor, int* __restrict__ outl, int E)
{
  int i = blockIdx.x*256 + threadIdx.x;
  if (i >= E) return;
  int p = atomicAdd(&cursor[key[i]], 1);
  outl[p] = val ? val[i] : i;
}

// one wave per destination node: leaky-relu logits, max, denom, weighted gather
__global__ __launch_bounds__(256)
void gat_gather(const int* __restrict__ rowptr, const int* __restrict__ csrc,
                const float* __restrict__ es, const float* __restrict__ ed,
                const float* __restrict__ Hv, const float* __restrict__ bias,
                float* __restrict__ out, int n)
{
  int d = blockIdx.x*4 + (threadIdx.x >> 6);
  int l = threadIdx.x & 63;
  if (d >= n) return;
  const int p0 = rowptr[d], p1 = rowptr[d+1];
  const float edd = ed[d];
  float eself = es[d] + edd;
  eself = eself > 0.f ? eself : 0.2f*eself;
  float m = eself;
  for (int j = p0 + l; j < p1; j += 64){
    int s = csrc[j];
    float e = es[s] + edd;
    e = e > 0.f ? e : 0.2f*e;
    m = fmaxf(m, e);
  }
  #pragma unroll
  for (int off = 1; off < 64; off <<= 1) m = fmaxf(m, __shfl_xor(m, off, 64));
  float part = 0.f;
  for (int j = p0 + l; j < p1; j += 64){
    int s = csrc[j];
    float e = es[s] + edd;
    e = e > 0.f ? e : 0.2f*e;
    part += __expf(e - m);
  }
  #pragma unroll
  for (int off = 1; off < 64; off <<= 1) part += __shfl_xor(part, off, 64);
  const float wself = __expf(eself - m);
  const float inv = 1.f/(part + wself);
  float a = wself*inv;
  float acc0 = a * Hv[(long)d*HSZ + l];
  float acc1 = a * Hv[(long)d*HSZ + 64 + l];
  for (int j = p0; j < p1; ++j){
    int s = csrc[j];
    float e = es[s] + edd;
    e = e > 0.f ? e : 0.2f*e;
    float al = __expf(e - m)*inv;
    acc0 += al * Hv[(long)s*HSZ + l];
    acc1 += al * Hv[(long)s*HSZ + 64 + l];
  }
  out[(long)d*HSZ + l]      = acc0 + bias[l];
  out[(long)d*HSZ + 64 + l] = acc1 + bias[64 + l];
}

// per-sector max pool using sector row-list (CSR over sid)
__global__ __launch_bounds__(256)
void sector_pool(const float* __restrict__ intra, const int* __restrict__ srowptr,
                 const int* __restrict__ slist, float* __restrict__ spool)
{
  const int sec = blockIdx.x;
  const int t = threadIdx.x;
  const int d = t & 127, half = t >> 7;
  const int p0 = srowptr[sec], p1 = srowptr[sec+1];
  float m = -3.402823466e+38f;
  for (int j = p0 + half; j < p1; j += 2){
    int r = slist[j];
    m = fmaxf(m, intra[(long)r*HSZ + d]);
  }
  __shared__ float red[256];
  red[t] = m;
  __syncthreads();
  if (half == 0) spool[sec*HSZ + d] = fmaxf(red[d], red[128 + d]);
}

// ---- inter-sector GAT (tiny, keep atomic path) ----
__global__ void gat_init(unsigned* __restrict__ maxb, float* __restrict__ den,
                         float* __restrict__ acc, int n)
{
  long i = (long)blockIdx.x*256 + threadIdx.x;
  if (i < n){ maxb[i] = NEG_MAX_ORD; den[i] = 0.f; }
  if (i < (long)n*HSZ) acc[i] = 0.f;
}

__global__ void edge_max(const int* __restrict__ src, const int* __restrict__ dst,
                         const float* __restrict__ es, const float* __restrict__ ed,
                         unsigned* __restrict__ maxb, int E, int n)
{
  int i = blockIdx.x*256 + threadIdx.x;
  if (i >= E + n) return;
  int s, d;
  if (i < E){ s = src[i]; d = dst[i]; } else { s = d = i - E; }
  float e = es[s] + ed[d];
  e = e > 0.f ? e : 0.2f*e;
  atomicMax(maxb + d, fordu(e));
}

__global__ void edge_sum(const int* __restrict__ src, const int* __restrict__ dst,
                         const float* __restrict__ es, const float* __restrict__ ed,
                         const unsigned* __restrict__ maxb, float* __restrict__ den,
                         float* __restrict__ wbuf, int E, int n)
{
  int i = blockIdx.x*256 + threadIdx.x;
  if (i >= E + n) return;
  int s, d;
  if (i < E){ s = src[i]; d = dst[i]; } else { s = d = i - E; }
  float e = es[s] + ed[d];
  e = e > 0.f ? e : 0.2f*e;
  float w = __expf(e - unfordu(maxb[d]));
  wbuf[i] = w;
  atomicAdd(den + d, w);
}

__global__ void edge_scatter(const int* __restrict__ src, const int* __restrict__ dst,
                             const float* __restrict__ wbuf, const float* __restrict__ den,
                             const float* __restrict__ Hv, float* __restrict__ acc,
                             int E, int n)
{
  long t = (long)blockIdx.x*256 + threadIdx.x;
  long i = t >> 5;
  int  j = (int)(t & 31);
  if (i >= E + n) return;
  int s, d;
  if (i < E){ s = src[i]; d = dst[i]; } else { s = d = (int)(i - E); }
  float alpha = wbuf[i] / den[d];
  float4 hv = ((const float4*)(Hv + (long)s*HSZ))[j];
  float* o = acc + (long)d*HSZ + j*4;
  atomicAdd(o+0, alpha*hv.x);
  atomicAdd(o+1, alpha*hv.y);
  atomicAdd(o+2, alpha*hv.z);
  atomicAdd(o+3, alpha*hv.w);
}

__global__ void inter_bias_k(const float* __restrict__ acc2, const float* __restrict__ bias,
                             float* __restrict__ isec)
{
  int i = blockIdx.x*256 + threadIdx.x;   // exactly 64*128
  isec[i] = acc2[i] + bias[i & 127];
}

__global__ __launch_bounds__(256)
void fusion_k(const float* __restrict__ seq, const float* __restrict__ intra,
              const float* __restrict__ isec, const int* __restrict__ sid,
              const float* __restrict__ fw, const float* __restrict__ fb,
              float* __restrict__ out, int n)
{
  int i = blockIdx.x*4 + (threadIdx.x >> 6);
  int l = threadIdx.x & 63;
  if (i >= n) return;
  int sc = sid[i];
  long b = (long)i*HSZ;
  long sb = (long)sc*HSZ;
  float acc = fw[l]     * seq[b + l]      + fw[64 + l]  * seq[b + 64 + l]
            + fw[128+l] * intra[b + l]    + fw[192 + l] * intra[b + 64 + l]
            + fw[256+l] * isec[sb + l]    + fw[320 + l] * isec[sb + 64 + l];
  #pragma unroll
  for (int m = 1; m < 64; m <<= 1) acc += __shfl_xor(acc, m, 64);
  if (l == 0) out[i] = acc + fb[0];
}

extern "C" void kernel_launch(void* const* d_in, const int* in_sizes, int n_in,
                              void* d_out, int out_size, void* d_ws, size_t ws_size,
                              hipStream_t stream)
{
  const float* x    = (const float*)d_in[0];
  const int*   iei  = (const int*)d_in[1];    // [2, 640000]
  const int*   eei  = (const int*)d_in[2];    // [2, 4096]
  const int*   sid  = (const int*)d_in[3];
  const float* wih0 = (const float*)d_in[4];
  const float* whh0 = (const float*)d_in[5];
  const float* bih0 = (const float*)d_in[6];
  const float* bhh0 = (const float*)d_in[7];
  const float* wih1 = (const float*)d_in[8];
  const float* whh1 = (const float*)d_in[9];
  const float* bih1 = (const float*)d_in[10];
  const float* bhh1 = (const float*)d_in[11];
  const float* iW   = (const float*)d_in[12];
  const float* ias  = (const float*)d_in[13];
  const float* iad  = (const float*)d_in[14];
  const float* ib   = (const float*)d_in[15];
  const float* eW   = (const float*)d_in[16];
  const float* eas  = (const float*)d_in[17];
  const float* ead  = (const float*)d_in[18];
  const float* eb   = (const float*)d_in[19];
  const float* fW   = (const float*)d_in[20];
  const float* fb   = (const float*)d_in[21];

  float* ws = (float*)d_ws;
  long off = 0;
  float* seq    = ws + off; off += 2560000;
  float* hintra = ws + off; off += 2560000;
  float* intra  = ws + off; off += 2560000;
  float* es     = ws + off; off += 20000;
  float* ed     = ws + off; off += 20000;
  int*   cnt    = (int*)(ws + off); off += 20000;
  int*   rowptr = (int*)(ws + off); off += 20004;
  int*   cursor = (int*)(ws + off); off += 20000;
  int*   csrc   = (int*)(ws + off); off += 640000;
  int*   scnt    = (int*)(ws + off); off += 64;
  int*   srowptr = (int*)(ws + off); off += 68;
  int*   scursor = (int*)(ws + off); off += 64;
  int*   slist   = (int*)(ws + off); off += 20000;
  float* w0p = ws + off; off += 24576;   // bf16x3 pack: 2kt*24nt*2*1024B
  float* u0p = ws + off; off += 49152;   // 4kt
  float* w1p = ws + off; off += 49152;
  float* u1p = ws + off; off += 49152;
  float* spool  = ws + off; off += 8192;
  float* hinter = ws + off; off += 8192;
  float* acc2   = ws + off; off += 8192;
  float* es2    = ws + off; off += 64;
  float* ed2    = ws + off; off += 64;
  unsigned* mx2 = (unsigned*)(ws + off); off += 64;
  float* den2   = ws + off; off += 64;
  float* wbf2   = ws + off; off += 4160;
  float* isec   = ws + off; off += 8192;
  // total ~8.6M floats = ~34.5 MB

  // 0) pack GRU weights into bf16 hi/lo MFMA fragment layout
  wpack_mfma<<<12, 256, 0, stream>>>(wih0, (unsigned short*)w0p, 64);
  wpack_mfma<<<24, 256, 0, stream>>>(whh0, (unsigned short*)u0p, 128);
  wpack_mfma<<<24, 256, 0, stream>>>(wih1, (unsigned short*)w1p, 128);
  wpack_mfma<<<24, 256, 0, stream>>>(whh1, (unsigned short*)u1p, 128);

  // 1) MFMA bf16x3 fused 2-layer GRU -> seq_emb (250 blocks x 512 thr, M=80)
  gru_mfma<<<250, 512, 0, stream>>>(x,
                                    (const unsigned short*)w0p, (const unsigned short*)u0p,
                                    (const unsigned short*)w1p, (const unsigned short*)u1p,
                                    bih0, bhh0, bih1, bhh1, seq);

  // 2) intra GAT: transform + CSR build + atomic-free gather
  gat_transform<<<313, 256, 0, stream>>>(seq, iW, ias, iad, hintra, es, ed, NCOMP);
  zero_i   <<<(NCOMP+255)/256, 256, 0, stream>>>(cnt, NCOMP);
  zero_i   <<<1, 256, 0, stream>>>(scnt, NSEC);
  csr_count<<<(EINTRA+255)/256, 256, 0, stream>>>(iei + EINTRA, cnt, EINTRA);
  csr_count<<<(NCOMP+255)/256, 256, 0, stream>>>(sid, scnt, NCOMP);
  csr_scan <<<1, 1024, 0, stream>>>(cnt, rowptr, cursor, NCOMP);
  csr_scan <<<1, 1024, 0, stream>>>(scnt, srowptr, scursor, NSEC);
  csr_fill <<<(EINTRA+255)/256, 256, 0, stream>>>(iei, iei + EINTRA, cursor, csrc, EINTRA);
  csr_fill <<<(NCOMP+255)/256, 256, 0, stream>>>(nullptr, sid, scursor, slist, NCOMP);
  gat_gather<<<NCOMP/4, 256, 0, stream>>>(rowptr, csrc, es, ed, hintra, ib, intra, NCOMP);

  // 3) per-sector max pool via sector row lists
  sector_pool<<<NSEC, 256, 0, stream>>>(intra, srowptr, slist, spool);

  // 4) inter GAT (tiny: 64 nodes, 4096 edges — atomic path)
  gat_init<<<32, 256, 0, stream>>>(mx2, den2, acc2, NSEC);
  gat_transform<<<1, 256, 0, stream>>>(spool, eW, eas, ead, hinter, es2, ed2, NSEC);
  {
    int tot = EINTER + NSEC;
    edge_max    <<<(tot+255)/256, 256, 0, stream>>>(eei, eei+EINTER, es2, ed2, mx2, EINTER, NSEC);
    edge_sum    <<<(tot+255)/256, 256, 0, stream>>>(eei, eei+EINTER, es2, ed2, mx2, den2, wbf2, EINTER, NSEC);
    edge_scatter<<<(tot*32)/256, 256, 0, stream>>>(eei, eei+EINTER, wbf2, den2, hinter, acc2, EINTER, NSEC);
  }
  inter_bias_k<<<32, 256, 0, stream>>>(acc2, eb, isec);

  // 5) fusion -> output [20000]
  fusion_k<<<NCOMP/4, 256, 0, stream>>>(seq, intra, isec, sid, fW, fb, (float*)d_out, NCOMP);
}

// Round 9
// 1842.091 us; speedup vs baseline: 4.2464x; 1.0028x over previous
//
#include <hip/hip_runtime.h>
#include <math.h>

// Problem constants
#define NCOMP 20000
#define SEQT  32
#define INSZ  64
#define HSZ   128
#define EINTRA 640000
#define EINTER 4096
#define NSEC  64

#define LDH 132   // padded LDS row stride (floats) for gat_transform

typedef __attribute__((ext_vector_type(8))) short bf16x8;   // 8 bf16 in 4 VGPRs
typedef __attribute__((ext_vector_type(4))) float f32x4;    // MFMA C/D frag

__device__ __forceinline__ float dot4f(float4 a, float4 b){
  return a.x*b.x + a.y*b.y + a.z*b.z + a.w*b.w;
}
__device__ __forceinline__ float sigm(float x){ return 1.f/(1.f + __expf(-x)); }
__device__ __forceinline__ float ftanh(float x){
  float cx = fminf(fmaxf(x, -15.f), 15.f);
  float e = __expf(2.f*cx);
  return (e - 1.f)/(e + 1.f);
}
// monotone float<->uint mapping so atomicMax works for signed floats (inter path)
__device__ __forceinline__ unsigned fordu(float f){
  unsigned b = __float_as_uint(f);
  return (b & 0x80000000u) ? ~b : (b | 0x80000000u);
}
__device__ __forceinline__ float unfordu(unsigned u){
  unsigned b = (u & 0x80000000u) ? (u & 0x7fffffffu) : ~u;
  return __uint_as_float(b);
}
#define NEG_MAX_ORD 0x00800000u   // fordu(-FLT_MAX)

// bf16 hi/lo split helpers (truncation split: w = hi + rem exactly, lo = bf16(rem))
__device__ __forceinline__ unsigned short bf16hi(float f){
  return (unsigned short)(__float_as_uint(f) >> 16);
}
__device__ __forceinline__ float bf16tof(unsigned short h){
  return __uint_as_float(((unsigned)h) << 16);
}

// ===========================================================================
// Weight packing for MFMA bf16x3: out[(kt*24+nt)*2+{hi,lo}][lane][8 bf16].
// Fragment convention (must match A-side): col n = lane&15 (within nt tile),
// k = kt*32 + (lane>>4)*8 + j.  One coalesced dwordx4 per fragment at use.
// (UNCHANGED from rounds 5-8 — layout verified correct by passing refchecks.)
// ===========================================================================
__global__ void wpack_mfma(const float* __restrict__ W, unsigned short* __restrict__ out, int K)
{
  int tid = blockIdx.x*256 + threadIdx.x;
  int KT = K >> 5;
  if (tid >= KT*24*64) return;
  int lane = tid & 63;
  int nt   = (tid >> 6) % 24;
  int kt   = (tid >> 6) / 24;
  int col  = nt*16 + (lane & 15);
  int kbase = kt*32 + (lane >> 4)*8;
  size_t b = ((size_t)(kt*24 + nt)*2*64 + lane)*8;   // hi at b, lo at b+512
  #pragma unroll
  for (int j = 0; j < 8; ++j){
    float w = W[(size_t)col*K + kbase + j];
    unsigned short h = bf16hi(w);
    float rem = w - bf16tof(h);
    out[b + j]       = h;
    out[b + 512 + j] = bf16hi(rem);
  }
}

// ===========================================================================
// MFMA bf16x3 fused 2-layer GRU, v3.2: register-residency inversion.
// Block = 512 thr (8 waves) = 80 companies (5 M-tiles), grid 250 (exact).
// Wave w owns dim-slice [16w, 16w+16) -> B-tiles {w, 8+w, 16+w} (R/Z/N).
// ROUND-8 DIAGNOSIS: compiler voluntarily picked a 128-VGPR schedule and
// spilled (~223MB/dispatch scratch writes) regardless of launch_bounds,
// because BGEMM held 10 A-frags (40 VGPR) live on top of 80 C-frag regs.
// v3.2 inverts residency: hold the 6 B-frags (24 VGPR) per slab, STREAM the
// A-frags (8 VGPR, dead after their 9 MFMAs). Peak live ~118 < 128 -> the
// 128-VGPR schedule needs no spill. Same LDS traffic, same MFMA count,
// same pack/hfr layouts, same bf16x3 math, same C/D map, 4 barriers/t.
// ===========================================================================
__global__ __launch_bounds__(512, 1)
void gru_mfma(const float* __restrict__ x,
              const unsigned short* __restrict__ w0pk, const unsigned short* __restrict__ u0pk,
              const unsigned short* __restrict__ w1pk, const unsigned short* __restrict__ u1pk,
              const float* __restrict__ bih0, const float* __restrict__ bhh0,
              const float* __restrict__ bih1, const float* __restrict__ bhh1,
              float* __restrict__ seq)
{
  // [layer][hi/lo][kt][mtile][lane][8] : 2*2*4*5*64*8*2B = 80 KB
  __shared__ __align__(16) unsigned short hfr[2][2][4][5][64][8];

  const int tid = threadIdx.x;
  const int w = tid >> 6, l = tid & 63;
  const int cq = l & 15, kg = l >> 4;
  const int cbase = blockIdx.x*80;          // 250*80 == 20000 exactly, no tail
  const int d = w*16 + cq;                  // this thread's output dim [0,128)
  const int ktp = d >> 5, kgp = (d >> 3) & 3, jp = d & 7;  // h-frag cell for dim d

  // zero h state
  {
    float4 z4 = make_float4(0.f,0.f,0.f,0.f);
    float4* hz = (float4*)&hfr[0][0][0][0][0][0];
    for (int i = tid; i < 5120; i += 512) hz[i] = z4;   // 80 KB
  }
  // biases in registers (dim d fixed per thread)
  const float bR0 = bih0[d]       + bhh0[d];
  const float bZ0 = bih0[128 + d] + bhh0[128 + d];
  const float bX0 = bih0[256 + d];
  const float bH0 = bhh0[256 + d];
  const float bR1 = bih1[d]       + bhh1[d];
  const float bZ1 = bih1[128 + d] + bhh1[128 + d];
  const float bX1 = bih1[256 + d];
  const float bH1 = bhh1[256 + d];
  __syncthreads();

  f32x4 cR[5], cZ[5], cN[5], cH[5];

  #define CINIT(BR,BZ,BX,BH) do { \
    _Pragma("unroll") for (int mt = 0; mt < 5; ++mt){ \
      cR[mt] = (f32x4){BR,BR,BR,BR}; \
      cZ[mt] = (f32x4){BZ,BZ,BZ,BZ}; \
      cN[mt] = (f32x4){BX,BX,BX,BX}; \
      cH[mt] = (f32x4){BH,BH,BH,BH}; } \
  } while(0)

  #define MF3(AH, AL, BH, BL, C) do { \
    C = __builtin_amdgcn_mfma_f32_16x16x32_bf16(AH, BH, C, 0,0,0); \
    C = __builtin_amdgcn_mfma_f32_16x16x32_bf16(AH, BL, C, 0,0,0); \
    C = __builtin_amdgcn_mfma_f32_16x16x32_bf16(AL, BH, C, 0,0,0); \
  } while(0)

  // one kt-slab, A = h fragments: 6 B-frags resident, A streamed per mt.
  #define GEMSLAB(PK, KT, LYR, C2) do { \
    const unsigned short* _p = (PK) + (size_t)(KT)*24576 + (size_t)l*8; \
    const bf16x8* bp0 = (const bf16x8*)(_p + (size_t)w*1024); \
    const bf16x8* bp1 = (const bf16x8*)(_p + (size_t)(8 + w)*1024); \
    const bf16x8* bp2 = (const bf16x8*)(_p + (size_t)(16 + w)*1024); \
    bf16x8 bh0 = bp0[0], bl0 = bp0[64]; \
    bf16x8 bh1 = bp1[0], bl1 = bp1[64]; \
    bf16x8 bh2 = bp2[0], bl2 = bp2[64]; \
    _Pragma("unroll") for (int mt = 0; mt < 5; ++mt){ \
      bf16x8 ah = *(const bf16x8*)&hfr[LYR][0][KT][mt][l][0]; \
      bf16x8 al = *(const bf16x8*)&hfr[LYR][1][KT][mt][l][0]; \
      MF3(ah, al, bh0, bl0, cR[mt]); \
      MF3(ah, al, bh1, bl1, cZ[mt]); \
      MF3(ah, al, bh2, bl2, C2[mt]); } \
  } while(0)

  // one kt-slab, A = x from global (layer-0, K=64): B resident, x per mt.
  #define GEMSLABX(KT) do { \
    const unsigned short* _p = w0pk + (size_t)(KT)*24576 + (size_t)l*8; \
    const bf16x8* bp0 = (const bf16x8*)(_p + (size_t)w*1024); \
    const bf16x8* bp1 = (const bf16x8*)(_p + (size_t)(8 + w)*1024); \
    const bf16x8* bp2 = (const bf16x8*)(_p + (size_t)(16 + w)*1024); \
    bf16x8 bh0 = bp0[0], bl0 = bp0[64]; \
    bf16x8 bh1 = bp1[0], bl1 = bp1[64]; \
    bf16x8 bh2 = bp2[0], bl2 = bp2[64]; \
    _Pragma("unroll") for (int mt = 0; mt < 5; ++mt){ \
      const float* xp = x + ((size_t)(cbase + mt*16 + cq)*SEQT + t)*INSZ + (KT)*32 + kg*8; \
      float4 q0 = *(const float4*)xp; \
      float4 q1 = *(const float4*)(xp + 4); \
      float xf[8] = {q0.x,q0.y,q0.z,q0.w, q1.x,q1.y,q1.z,q1.w}; \
      bf16x8 ah, al; \
      _Pragma("unroll") for (int j = 0; j < 8; ++j){ \
        unsigned short h_ = bf16hi(xf[j]); \
        ah[j] = (short)h_; \
        al[j] = (short)bf16hi(xf[j] - bf16tof(h_)); } \
      MF3(ah, al, bh0, bl0, cR[mt]); \
      MF3(ah, al, bh1, bl1, cZ[mt]); \
      MF3(ah, al, bh2, bl2, cN[mt]); } \
  } while(0)

  // GRU elementwise for this thread's dim d across 5 mt x 4 comps.
  // C/D layout (m89-verified): col=cq (dim-in-tile), row=kg*4+r (comp).
  #define ELEM(LYR, DOSTORE) do { \
    _Pragma("unroll") for (int mt = 0; mt < 5; ++mt){ \
      unsigned short* hhi = &hfr[LYR][0][ktp][mt][0][0]; \
      unsigned short* hlo = &hfr[LYR][1][ktp][mt][0][0]; \
      _Pragma("unroll") for (int r = 0; r < 4; ++r){ \
        int lanep = kgp*16 + kg*4 + r; \
        float hold = bf16tof(hhi[lanep*8 + jp]) + bf16tof(hlo[lanep*8 + jp]); \
        float rr = sigm(cR[mt][r]); \
        float zz = sigm(cZ[mt][r]); \
        float nn = ftanh(cN[mt][r] + rr*cH[mt][r]); \
        float hn = (1.f - zz)*nn + zz*hold; \
        unsigned short hh = bf16hi(hn); \
        hhi[lanep*8 + jp] = hh; \
        hlo[lanep*8 + jp] = bf16hi(hn - bf16tof(hh)); \
        if (DOSTORE) seq[(size_t)(cbase + mt*16 + kg*4 + r)*HSZ + d] = hn; } } \
  } while(0)

  #pragma unroll 1
  for (int t = 0; t < SEQT; ++t){
    // ================= layer 0 =================
    CINIT(bR0, bZ0, bX0, bH0);
    GEMSLABX(0);                       // x part, K=64
    GEMSLABX(1);
    GEMSLAB(u0pk, 0, 0, cH);           // h part, K=128 (A = h0_old)
    GEMSLAB(u0pk, 1, 0, cH);
    GEMSLAB(u0pk, 2, 0, cH);
    GEMSLAB(u0pk, 3, 0, cH);
    __syncthreads();                   // all waves done reading h0_old
    ELEM(0, false);
    __syncthreads();                   // h0_new visible
    // ================= layer 1 =================
    CINIT(bR1, bZ1, bX1, bH1);
    GEMSLAB(w1pk, 0, 0, cN);           // input = h0_new
    GEMSLAB(w1pk, 1, 0, cN);
    GEMSLAB(w1pk, 2, 0, cN);
    GEMSLAB(w1pk, 3, 0, cN);
    GEMSLAB(u1pk, 0, 1, cH);           // hidden h1_old
    GEMSLAB(u1pk, 1, 1, cH);
    GEMSLAB(u1pk, 2, 1, cH);
    GEMSLAB(u1pk, 3, 1, cH);
    __syncthreads();                   // all waves done reading h1_old
    ELEM(1, (t == SEQT-1));
    __syncthreads();                   // h1_new visible for next t
  }
  #undef CINIT
  #undef MF3
  #undef GEMSLAB
  #undef GEMSLABX
  #undef ELEM
}

// ===========================================================================
// GAT stage — CSR build + atomic-free per-node gather
// ===========================================================================
__global__ __launch_bounds__(256)
void gat_transform(const float* __restrict__ X, const float* __restrict__ W,
                   const float* __restrict__ asrc, const float* __restrict__ adst,
                   float* __restrict__ Hout, float* __restrict__ es, float* __restrict__ ed,
                   int n)
{
  __shared__ float sX[64*LDH];
  const int tid = threadIdx.x;
  const long base = (long)blockIdx.x * 64;
  for (int i = tid; i < 64*32; i += 256){
    int row = i >> 5, q = i & 31;
    long gr = base + row;
    float4 v = make_float4(0.f, 0.f, 0.f, 0.f);
    if (gr < n) v = ((const float4*)(X + gr*HSZ))[q];
    ((float4*)(sX + row*LDH))[q] = v;
  }
  __syncthreads();
  const int rp = tid >> 3, dg = tid & 7;
  const int r0 = rp*2, r1 = r0 + 1;
  const float4* xa = (const float4*)(sX + r0*LDH);
  const float4* xb = (const float4*)(sX + r1*LDH);
  float ps0=0.f, pd0=0.f, ps1=0.f, pd1=0.f;
  for (int dd = 0; dd < 16; ++dd){
    const int cidx = dg*16 + dd;
    const float4* wp = (const float4*)(W + cidx*HSZ);
    float a0 = 0.f, a1 = 0.f;
    #pragma unroll 4
    for (int q = 0; q < 32; ++q){
      float4 w = wp[q];
      a0 += dot4f(w, xa[q]);
      a1 += dot4f(w, xb[q]);
    }
    float s = asrc[cidx], dv = adst[cidx];
    ps0 += a0*s; pd0 += a0*dv;
    ps1 += a1*s; pd1 += a1*dv;
    if (base + r0 < n) Hout[(base+r0)*HSZ + cidx] = a0;
    if (base + r1 < n) Hout[(base+r1)*HSZ + cidx] = a1;
  }
  #pragma unroll
  for (int m = 1; m < 8; m <<= 1){
    ps0 += __shfl_xor(ps0, m, 64);
    pd0 += __shfl_xor(pd0, m, 64);
    ps1 += __shfl_xor(ps1, m, 64);
    pd1 += __shfl_xor(pd1, m, 64);
  }
  if (dg == 0){
    if (base + r0 < n){ es[base+r0] = ps0; ed[base+r0] = pd0; }
    if (base + r1 < n){ es[base+r1] = ps1; ed[base+r1] = pd1; }
  }
}

__global__ void zero_i(int* __restrict__ p, int n)
{
  int i = blockIdx.x*256 + threadIdx.x;
  if (i < n) p[i] = 0;
}

__global__ void csr_count(const int* __restrict__ key, int* __restrict__ cnt, int E)
{
  int i = blockIdx.x*256 + threadIdx.x;
  if (i < E) atomicAdd(&cnt[key[i]], 1);
}

// single block, 1024 threads: exclusive scan of cnt[0..n) -> rowptr, cursor
__global__ __launch_bounds__(1024)
void csr_scan(const int* __restrict__ cnt, int* __restrict__ rowptr,
              int* __restrict__ cursor, int n)
{
  __shared__ int ls[1024];
  const int t = threadIdx.x;
  const int base = t*20;
  int loc[20];
  int s = 0;
  #pragma unroll
  for (int k = 0; k < 20; ++k){
    int idx = base + k;
    int v = (idx < n) ? cnt[idx] : 0;
    loc[k] = s; s += v;
  }
  ls[t] = s;
  __syncthreads();
  for (int off = 1; off < 1024; off <<= 1){
    int v = (t >= off) ? ls[t-off] : 0;
    __syncthreads();
    ls[t] += v;
    __syncthreads();
  }
  int excl = (t == 0) ? 0 : ls[t-1];
  #pragma unroll
  for (int k = 0; k < 20; ++k){
    int idx = base + k;
    if (idx < n){ int rp = excl + loc[k]; rowptr[idx] = rp; cursor[idx] = rp; }
  }
  if (t == 1023) rowptr[n] = ls[1023];
}

// val==nullptr -> store the element index i (used for sector row lists)
__global__ void csr_fill(const int* __restrict__ val, const int* __restrict__ key,
                         int* __restrict__ cursor, int* __restrict__ outl, int E)
{
  int i = blockIdx.x*256 + threadIdx.x;
  if (i >= E) return;
  int p = atomicAdd(&cursor[key[i]], 1);
  outl[p] = val ? val[i] : i;
}

// one wave per destination node: leaky-relu logits, max, denom, weighted gather
__global__ __launch_bounds__(256)
void gat_gather(const int* __restrict__ rowptr, const int* __restrict__ csrc,
                const float* __restrict__ es, const float* __restrict__ ed,
                const float* __restrict__ Hv, const float* __restrict__ bias,
                float* __restrict__ out, int n)
{
  int d = blockIdx.x*4 + (threadIdx.x >> 6);
  int l = threadIdx.x & 63;
  if (d >= n) return;
  const int p0 = rowptr[d], p1 = rowptr[d+1];
  const float edd = ed[d];
  float eself = es[d] + edd;
  eself = eself > 0.f ? eself : 0.2f*eself;
  float m = eself;
  for (int j = p0 + l; j < p1; j += 64){
    int s = csrc[j];
    float e = es[s] + edd;
    e = e > 0.f ? e : 0.2f*e;
    m = fmaxf(m, e);
  }
  #pragma unroll
  for (int off = 1; off < 64; off <<= 1) m = fmaxf(m, __shfl_xor(m, off, 64));
  float part = 0.f;
  for (int j = p0 + l; j < p1; j += 64){
    int s = csrc[j];
    float e = es[s] + edd;
    e = e > 0.f ? e : 0.2f*e;
    part += __expf(e - m);
  }
  #pragma unroll
  for (int off = 1; off < 64; off <<= 1) part += __shfl_xor(part, off, 64);
  const float wself = __expf(eself - m);
  const float inv = 1.f/(part + wself);
  float a = wself*inv;
  float acc0 = a * Hv[(long)d*HSZ + l];
  float acc1 = a * Hv[(long)d*HSZ + 64 + l];
  for (int j = p0; j < p1; ++j){
    int s = csrc[j];
    float e = es[s] + edd;
    e = e > 0.f ? e : 0.2f*e;
    float al = __expf(e - m)*inv;
    acc0 += al * Hv[(long)s*HSZ + l];
    acc1 += al * Hv[(long)s*HSZ + 64 + l];
  }
  out[(long)d*HSZ + l]      = acc0 + bias[l];
  out[(long)d*HSZ + 64 + l] = acc1 + bias[64 + l];
}

// per-sector max pool using sector row-list (CSR over sid)
__global__ __launch_bounds__(256)
void sector_pool(const float* __restrict__ intra, const int* __restrict__ srowptr,
                 const int* __restrict__ slist, float* __restrict__ spool)
{
  const int sec = blockIdx.x;
  const int t = threadIdx.x;
  const int d = t & 127, half = t >> 7;
  const int p0 = srowptr[sec], p1 = srowptr[sec+1];
  float m = -3.402823466e+38f;
  for (int j = p0 + half; j < p1; j += 2){
    int r = slist[j];
    m = fmaxf(m, intra[(long)r*HSZ + d]);
  }
  __shared__ float red[256];
  red[t] = m;
  __syncthreads();
  if (half == 0) spool[sec*HSZ + d] = fmaxf(red[d], red[128 + d]);
}

// ---- inter-sector GAT (tiny, keep atomic path) ----
__global__ void gat_init(unsigned* __restrict__ maxb, float* __restrict__ den,
                         float* __restrict__ acc, int n)
{
  long i = (long)blockIdx.x*256 + threadIdx.x;
  if (i < n){ maxb[i] = NEG_MAX_ORD; den[i] = 0.f; }
  if (i < (long)n*HSZ) acc[i] = 0.f;
}

__global__ void edge_max(const int* __restrict__ src, const int* __restrict__ dst,
                         const float* __restrict__ es, const float* __restrict__ ed,
                         unsigned* __restrict__ maxb, int E, int n)
{
  int i = blockIdx.x*256 + threadIdx.x;
  if (i >= E + n) return;
  int s, d;
  if (i < E){ s = src[i]; d = dst[i]; } else { s = d = i - E; }
  float e = es[s] + ed[d];
  e = e > 0.f ? e : 0.2f*e;
  atomicMax(maxb + d, fordu(e));
}

__global__ void edge_sum(const int* __restrict__ src, const int* __restrict__ dst,
                         const float* __restrict__ es, const float* __restrict__ ed,
                         const unsigned* __restrict__ maxb, float* __restrict__ den,
                         float* __restrict__ wbuf, int E, int n)
{
  int i = blockIdx.x*256 + threadIdx.x;
  if (i >= E + n) return;
  int s, d;
  if (i < E){ s = src[i]; d = dst[i]; } else { s = d = i - E; }
  float e = es[s] + ed[d];
  e = e > 0.f ? e : 0.2f*e;
  float w = __expf(e - unfordu(maxb[d]));
  wbuf[i] = w;
  atomicAdd(den + d, w);
}

__global__ void edge_scatter(const int* __restrict__ src, const int* __restrict__ dst,
                             const float* __restrict__ wbuf, const float* __restrict__ den,
                             const float* __restrict__ Hv, float* __restrict__ acc,
                             int E, int n)
{
  long t = (long)blockIdx.x*256 + threadIdx.x;
  long i = t >> 5;
  int  j = (int)(t & 31);
  if (i >= E + n) return;
  int s, d;
  if (i < E){ s = src[i]; d = dst[i]; } else { s = d = (int)(i - E); }
  float alpha = wbuf[i] / den[d];
  float4 hv = ((const float4*)(Hv + (long)s*HSZ))[j];
  float* o = acc + (long)d*HSZ + j*4;
  atomicAdd(o+0, alpha*hv.x);
  atomicAdd(o+1, alpha*hv.y);
  atomicAdd(o+2, alpha*hv.z);
  atomicAdd(o+3, alpha*hv.w);
}

__global__ void inter_bias_k(const float* __restrict__ acc2, const float* __restrict__ bias,
                             float* __restrict__ isec)
{
  int i = blockIdx.x*256 + threadIdx.x;   // exactly 64*128
  isec[i] = acc2[i] + bias[i & 127];
}

__global__ __launch_bounds__(256)
void fusion_k(const float* __restrict__ seq, const float* __restrict__ intra,
              const float* __restrict__ isec, const int* __restrict__ sid,
              const float* __restrict__ fw, const float* __restrict__ fb,
              float* __restrict__ out, int n)
{
  int i = blockIdx.x*4 + (threadIdx.x >> 6);
  int l = threadIdx.x & 63;
  if (i >= n) return;
  int sc = sid[i];
  long b = (long)i*HSZ;
  long sb = (long)sc*HSZ;
  float acc = fw[l]     * seq[b + l]      + fw[64 + l]  * seq[b + 64 + l]
            + fw[128+l] * intra[b + l]    + fw[192 + l] * intra[b + 64 + l]
            + fw[256+l] * isec[sb + l]    + fw[320 + l] * isec[sb + 64 + l];
  #pragma unroll
  for (int m = 1; m < 64; m <<= 1) acc += __shfl_xor(acc, m, 64);
  if (l == 0) out[i] = acc + fb[0];
}

extern "C" void kernel_launch(void* const* d_in, const int* in_sizes, int n_in,
                              void* d_out, int out_size, void* d_ws, size_t ws_size,
                              hipStream_t stream)
{
  const float* x    = (const float*)d_in[0];
  const int*   iei  = (const int*)d_in[1];    // [2, 640000]
  const int*   eei  = (const int*)d_in[2];    // [2, 4096]
  const int*   sid  = (const int*)d_in[3];
  const float* wih0 = (const float*)d_in[4];
  const float* whh0 = (const float*)d_in[5];
  const float* bih0 = (const float*)d_in[6];
  const float* bhh0 = (const float*)d_in[7];
  const float* wih1 = (const float*)d_in[8];
  const float* whh1 = (const float*)d_in[9];
  const float* bih1 = (const float*)d_in[10];
  const float* bhh1 = (const float*)d_in[11];
  const float* iW   = (const float*)d_in[12];
  const float* ias  = (const float*)d_in[13];
  const float* iad  = (const float*)d_in[14];
  const float* ib   = (const float*)d_in[15];
  const float* eW   = (const float*)d_in[16];
  const float* eas  = (const float*)d_in[17];
  const float* ead  = (const float*)d_in[18];
  const float* eb   = (const float*)d_in[19];
  const float* fW   = (const float*)d_in[20];
  const float* fb   = (const float*)d_in[21];

  float* ws = (float*)d_ws;
  long off = 0;
  float* seq    = ws + off; off += 2560000;
  float* hintra = ws + off; off += 2560000;
  float* intra  = ws + off; off += 2560000;
  float* es     = ws + off; off += 20000;
  float* ed     = ws + off; off += 20000;
  int*   cnt    = (int*)(ws + off); off += 20000;
  int*   rowptr = (int*)(ws + off); off += 20004;
  int*   cursor = (int*)(ws + off); off += 20000;
  int*   csrc   = (int*)(ws + off); off += 640000;
  int*   scnt    = (int*)(ws + off); off += 64;
  int*   srowptr = (int*)(ws + off); off += 68;
  int*   scursor = (int*)(ws + off); off += 64;
  int*   slist   = (int*)(ws + off); off += 20000;
  float* w0p = ws + off; off += 24576;   // bf16x3 pack: 2kt*24nt*2*1024B
  float* u0p = ws + off; off += 49152;   // 4kt
  float* w1p = ws + off; off += 49152;
  float* u1p = ws + off; off += 49152;
  float* spool  = ws + off; off += 8192;
  float* hinter = ws + off; off += 8192;
  float* acc2   = ws + off; off += 8192;
  float* es2    = ws + off; off += 64;
  float* ed2    = ws + off; off += 64;
  unsigned* mx2 = (unsigned*)(ws + off); off += 64;
  float* den2   = ws + off; off += 64;
  float* wbf2   = ws + off; off += 4160;
  float* isec   = ws + off; off += 8192;
  // total ~8.6M floats = ~34.5 MB

  // 0) pack GRU weights into bf16 hi/lo MFMA fragment layout
  wpack_mfma<<<12, 256, 0, stream>>>(wih0, (unsigned short*)w0p, 64);
  wpack_mfma<<<24, 256, 0, stream>>>(whh0, (unsigned short*)u0p, 128);
  wpack_mfma<<<24, 256, 0, stream>>>(wih1, (unsigned short*)w1p, 128);
  wpack_mfma<<<24, 256, 0, stream>>>(whh1, (unsigned short*)u1p, 128);

  // 1) MFMA bf16x3 fused 2-layer GRU -> seq_emb (250 blocks x 512 thr, M=80)
  gru_mfma<<<250, 512, 0, stream>>>(x,
                                    (const unsigned short*)w0p, (const unsigned short*)u0p,
                                    (const unsigned short*)w1p, (const unsigned short*)u1p,
                                    bih0, bhh0, bih1, bhh1, seq);

  // 2) intra GAT: transform + CSR build + atomic-free gather
  gat_transform<<<313, 256, 0, stream>>>(seq, iW, ias, iad, hintra, es, ed, NCOMP);
  zero_i   <<<(NCOMP+255)/256, 256, 0, stream>>>(cnt, NCOMP);
  zero_i   <<<1, 256, 0, stream>>>(scnt, NSEC);
  csr_count<<<(EINTRA+255)/256, 256, 0, stream>>>(iei + EINTRA, cnt, EINTRA);
  csr_count<<<(NCOMP+255)/256, 256, 0, stream>>>(sid, scnt, NCOMP);
  csr_scan <<<1, 1024, 0, stream>>>(cnt, rowptr, cursor, NCOMP);
  csr_scan <<<1, 1024, 0, stream>>>(scnt, srowptr, scursor, NSEC);
  csr_fill <<<(EINTRA+255)/256, 256, 0, stream>>>(iei, iei + EINTRA, cursor, csrc, EINTRA);
  csr_fill <<<(NCOMP+255)/256, 256, 0, stream>>>(nullptr, sid, scursor, slist, NCOMP);
  gat_gather<<<NCOMP/4, 256, 0, stream>>>(rowptr, csrc, es, ed, hintra, ib, intra, NCOMP);

  // 3) per-sector max pool via sector row lists
  sector_pool<<<NSEC, 256, 0, stream>>>(intra, srowptr, slist, spool);

  // 4) inter GAT (tiny: 64 nodes, 4096 edges — atomic path)
  gat_init<<<32, 256, 0, stream>>>(mx2, den2, acc2, NSEC);
  gat_transform<<<1, 256, 0, stream>>>(spool, eW, eas, ead, hinter, es2, ed2, NSEC);
  {
    int tot = EINTER + NSEC;
    edge_max    <<<(tot+255)/256, 256, 0, stream>>>(eei, eei+EINTER, es2, ed2, mx2, EINTER, NSEC);
    edge_sum    <<<(tot+255)/256, 256, 0, stream>>>(eei, eei+EINTER, es2, ed2, mx2, den2, wbf2, EINTER, NSEC);
    edge_scatter<<<(tot*32)/256, 256, 0, stream>>>(eei, eei+EINTER, wbf2, den2, hinter, acc2, EINTER, NSEC);
  }
  inter_bias_k<<<32, 256, 0, stream>>>(acc2, eb, isec);

  // 5) fusion -> output [20000]
  fusion_k<<<NCOMP/4, 256, 0, stream>>>(seq, intra, isec, sid, fW, fb, (float*)d_out, NCOMP);
}

// Round 10
// 1658.514 us; speedup vs baseline: 4.7165x; 1.1107x over previous
//
#include <hip/hip_runtime.h>
#include <math.h>

// Problem constants
#define NCOMP 20000
#define SEQT  32
#define INSZ  64
#define HSZ   128
#define EINTRA 640000
#define EINTER 4096
#define NSEC  64

#define LDH 132   // padded LDS row stride (floats) for gat_transform

typedef __attribute__((ext_vector_type(8))) short bf16x8;   // 8 bf16 in 4 VGPRs
typedef __attribute__((ext_vector_type(4))) float f32x4;    // MFMA C/D frag

__device__ __forceinline__ float dot4f(float4 a, float4 b){
  return a.x*b.x + a.y*b.y + a.z*b.z + a.w*b.w;
}
__device__ __forceinline__ float sigm(float x){ return 1.f/(1.f + __expf(-x)); }
__device__ __forceinline__ float ftanh(float x){
  float cx = fminf(fmaxf(x, -15.f), 15.f);
  float e = __expf(2.f*cx);
  return (e - 1.f)/(e + 1.f);
}
// monotone float<->uint mapping so atomicMax works for signed floats (inter path)
__device__ __forceinline__ unsigned fordu(float f){
  unsigned b = __float_as_uint(f);
  return (b & 0x80000000u) ? ~b : (b | 0x80000000u);
}
__device__ __forceinline__ float unfordu(unsigned u){
  unsigned b = (u & 0x80000000u) ? (u & 0x7fffffffu) : ~u;
  return __uint_as_float(b);
}
#define NEG_MAX_ORD 0x00800000u   // fordu(-FLT_MAX)

// bf16 hi/lo split helpers (truncation split: w = hi + rem exactly, lo = bf16(rem))
__device__ __forceinline__ unsigned short bf16hi(float f){
  return (unsigned short)(__float_as_uint(f) >> 16);
}
__device__ __forceinline__ float bf16tof(unsigned short h){
  return __uint_as_float(((unsigned)h) << 16);
}

// ===========================================================================
// Weight packing for MFMA bf16x3: out[(kt*24+nt)*2+{hi,lo}][lane][8 bf16].
// Fragment convention (must match A-side): col n = lane&15 (within nt tile),
// k = kt*32 + (lane>>4)*8 + j.  One coalesced dwordx4 per fragment at use.
// (UNCHANGED from rounds 5-9 — layout verified correct by passing refchecks.)
// ===========================================================================
__global__ void wpack_mfma(const float* __restrict__ W, unsigned short* __restrict__ out, int K)
{
  int tid = blockIdx.x*256 + threadIdx.x;
  int KT = K >> 5;
  if (tid >= KT*24*64) return;
  int lane = tid & 63;
  int nt   = (tid >> 6) % 24;
  int kt   = (tid >> 6) / 24;
  int col  = nt*16 + (lane & 15);
  int kbase = kt*32 + (lane >> 4)*8;
  size_t b = ((size_t)(kt*24 + nt)*2*64 + lane)*8;   // hi at b, lo at b+512
  #pragma unroll
  for (int j = 0; j < 8; ++j){
    float w = W[(size_t)col*K + kbase + j];
    unsigned short h = bf16hi(w);
    float rem = w - bf16tof(h);
    out[b + j]       = h;
    out[b + 512 + j] = bf16hi(rem);
  }
}

// ===========================================================================
// MFMA bf16x3 fused 2-layer GRU, v3.3: x deduplicated through LDS.
// Block = 512 thr (8 waves) = 80 companies (5 M-tiles), grid 250 (exact).
// Wave w owns dim-slice [16w, 16w+16) -> B-tiles {w, 8+w, 16+w} (R/Z/N).
// ROUND-9 DIAGNOSIS: FETCH 2.1 GB vs ~0.35 GB ideal. GEMSLABX's x loads +
// fp32->bf16x3 conversion were IDENTICAL across all 8 waves (address did
// not depend on w): 8x duplicated load issue, 8x duplicated convert VALU,
// 1.3 GB of redundant L2 requests thrashing the weight working set.
// v3.3: STAGEX converts x once per block per t into xfr LDS (20.5 KB);
// GEMSLABX reads A-frags from LDS exactly like GEMSLAB. Staged for t+1
// after ELEM(1) (xfr(t) reads finish before sync#1 -> no extra barrier).
// Arithmetic bit-identical. LDS 80->100.5 KB (still 1 block/CU; grid 250).
// ===========================================================================
__global__ __launch_bounds__(512, 1)
void gru_mfma(const float* __restrict__ x,
              const unsigned short* __restrict__ w0pk, const unsigned short* __restrict__ u0pk,
              const unsigned short* __restrict__ w1pk, const unsigned short* __restrict__ u1pk,
              const float* __restrict__ bih0, const float* __restrict__ bhh0,
              const float* __restrict__ bih1, const float* __restrict__ bhh1,
              float* __restrict__ seq)
{
  // [layer][hi/lo][kt][mtile][lane][8] : 2*2*4*5*64*8*2B = 80 KB
  __shared__ __align__(16) unsigned short hfr[2][2][4][5][64][8];
  // x fragments for current t: [kt][mtile][hi/lo][lane][8] = 20.5 KB
  __shared__ __align__(16) unsigned short xfr[2][5][2][64][8];

  const int tid = threadIdx.x;
  const int w = tid >> 6, l = tid & 63;
  const int cq = l & 15, kg = l >> 4;
  const int cbase = blockIdx.x*80;          // 250*80 == 20000 exactly, no tail
  const int d = w*16 + cq;                  // this thread's output dim [0,128)
  const int ktp = d >> 5, kgp = (d >> 3) & 3, jp = d & 7;  // h-frag cell for dim d

  // zero h state
  {
    float4 z4 = make_float4(0.f,0.f,0.f,0.f);
    float4* hz = (float4*)&hfr[0][0][0][0][0][0];
    for (int i = tid; i < 5120; i += 512) hz[i] = z4;   // 80 KB
  }
  // biases in registers (dim d fixed per thread)
  const float bR0 = bih0[d]       + bhh0[d];
  const float bZ0 = bih0[128 + d] + bhh0[128 + d];
  const float bX0 = bih0[256 + d];
  const float bH0 = bhh0[256 + d];
  const float bR1 = bih1[d]       + bhh1[d];
  const float bZ1 = bih1[128 + d] + bhh1[128 + d];
  const float bX1 = bih1[256 + d];
  const float bH1 = bhh1[256 + d];

  // stage x fragments for a timestep TT into xfr (once per block, not per wave).
  // fi covers (mt 0..4, kt 0..1, lane 0..63): each thread converts one 8-elem
  // fragment pair (hi+lo). ds_write_b128 lane-sequential => conflict-free.
  #define STAGEX(TT) do { \
    _Pragma("unroll") for (int it = 0; it < 2; ++it){ \
      int fi = tid + it*512; \
      if (fi < 640){ \
        int slane = fi & 63, q = fi >> 6; \
        int skt = q & 1, smt = q >> 1; \
        const float* sp = x + ((size_t)(cbase + smt*16 + (slane & 15))*SEQT + (TT))*INSZ \
                            + skt*32 + (slane >> 4)*8; \
        float4 q0 = *(const float4*)sp; \
        float4 q1 = *(const float4*)(sp + 4); \
        float xf[8] = {q0.x,q0.y,q0.z,q0.w, q1.x,q1.y,q1.z,q1.w}; \
        bf16x8 hv, lv; \
        _Pragma("unroll") for (int j = 0; j < 8; ++j){ \
          unsigned short h_ = bf16hi(xf[j]); \
          hv[j] = (short)h_; \
          lv[j] = (short)bf16hi(xf[j] - bf16tof(h_)); } \
        *(bf16x8*)&xfr[skt][smt][0][slane][0] = hv; \
        *(bf16x8*)&xfr[skt][smt][1][slane][0] = lv; } } \
  } while(0)

  STAGEX(0);
  __syncthreads();

  f32x4 cR[5], cZ[5], cN[5], cH[5];

  #define CINIT(BR,BZ,BX,BH) do { \
    _Pragma("unroll") for (int mt = 0; mt < 5; ++mt){ \
      cR[mt] = (f32x4){BR,BR,BR,BR}; \
      cZ[mt] = (f32x4){BZ,BZ,BZ,BZ}; \
      cN[mt] = (f32x4){BX,BX,BX,BX}; \
      cH[mt] = (f32x4){BH,BH,BH,BH}; } \
  } while(0)

  #define MF3(AH, AL, BH, BL, C) do { \
    C = __builtin_amdgcn_mfma_f32_16x16x32_bf16(AH, BH, C, 0,0,0); \
    C = __builtin_amdgcn_mfma_f32_16x16x32_bf16(AH, BL, C, 0,0,0); \
    C = __builtin_amdgcn_mfma_f32_16x16x32_bf16(AL, BH, C, 0,0,0); \
  } while(0)

  // one kt-slab, A = h fragments: 6 B-frags resident, A streamed per mt.
  #define GEMSLAB(PK, KT, LYR, C2) do { \
    const unsigned short* _p = (PK) + (size_t)(KT)*24576 + (size_t)l*8; \
    const bf16x8* bp0 = (const bf16x8*)(_p + (size_t)w*1024); \
    const bf16x8* bp1 = (const bf16x8*)(_p + (size_t)(8 + w)*1024); \
    const bf16x8* bp2 = (const bf16x8*)(_p + (size_t)(16 + w)*1024); \
    bf16x8 bh0 = bp0[0], bl0 = bp0[64]; \
    bf16x8 bh1 = bp1[0], bl1 = bp1[64]; \
    bf16x8 bh2 = bp2[0], bl2 = bp2[64]; \
    _Pragma("unroll") for (int mt = 0; mt < 5; ++mt){ \
      bf16x8 ah = *(const bf16x8*)&hfr[LYR][0][KT][mt][l][0]; \
      bf16x8 al = *(const bf16x8*)&hfr[LYR][1][KT][mt][l][0]; \
      MF3(ah, al, bh0, bl0, cR[mt]); \
      MF3(ah, al, bh1, bl1, cZ[mt]); \
      MF3(ah, al, bh2, bl2, C2[mt]); } \
  } while(0)

  // one kt-slab, A = staged x fragments from LDS (layer-0 input, K=64)
  #define GEMSLABX(KT) do { \
    const unsigned short* _p = w0pk + (size_t)(KT)*24576 + (size_t)l*8; \
    const bf16x8* bp0 = (const bf16x8*)(_p + (size_t)w*1024); \
    const bf16x8* bp1 = (const bf16x8*)(_p + (size_t)(8 + w)*1024); \
    const bf16x8* bp2 = (const bf16x8*)(_p + (size_t)(16 + w)*1024); \
    bf16x8 bh0 = bp0[0], bl0 = bp0[64]; \
    bf16x8 bh1 = bp1[0], bl1 = bp1[64]; \
    bf16x8 bh2 = bp2[0], bl2 = bp2[64]; \
    _Pragma("unroll") for (int mt = 0; mt < 5; ++mt){ \
      bf16x8 ah = *(const bf16x8*)&xfr[KT][mt][0][l][0]; \
      bf16x8 al = *(const bf16x8*)&xfr[KT][mt][1][l][0]; \
      MF3(ah, al, bh0, bl0, cR[mt]); \
      MF3(ah, al, bh1, bl1, cZ[mt]); \
      MF3(ah, al, bh2, bl2, cN[mt]); } \
  } while(0)

  // GRU elementwise for this thread's dim d across 5 mt x 4 comps.
  // C/D layout (m89-verified): col=cq (dim-in-tile), row=kg*4+r (comp).
  #define ELEM(LYR, DOSTORE) do { \
    _Pragma("unroll") for (int mt = 0; mt < 5; ++mt){ \
      unsigned short* hhi = &hfr[LYR][0][ktp][mt][0][0]; \
      unsigned short* hlo = &hfr[LYR][1][ktp][mt][0][0]; \
      _Pragma("unroll") for (int r = 0; r < 4; ++r){ \
        int lanep = kgp*16 + kg*4 + r; \
        float hold = bf16tof(hhi[lanep*8 + jp]) + bf16tof(hlo[lanep*8 + jp]); \
        float rr = sigm(cR[mt][r]); \
        float zz = sigm(cZ[mt][r]); \
        float nn = ftanh(cN[mt][r] + rr*cH[mt][r]); \
        float hn = (1.f - zz)*nn + zz*hold; \
        unsigned short hh = bf16hi(hn); \
        hhi[lanep*8 + jp] = hh; \
        hlo[lanep*8 + jp] = bf16hi(hn - bf16tof(hh)); \
        if (DOSTORE) seq[(size_t)(cbase + mt*16 + kg*4 + r)*HSZ + d] = hn; } } \
  } while(0)

  #pragma unroll 1
  for (int t = 0; t < SEQT; ++t){
    // ================= layer 0 =================
    CINIT(bR0, bZ0, bX0, bH0);
    GEMSLABX(0);                       // x part, K=64 (A from staged LDS)
    GEMSLABX(1);
    GEMSLAB(u0pk, 0, 0, cH);           // h part, K=128 (A = h0_old)
    GEMSLAB(u0pk, 1, 0, cH);
    GEMSLAB(u0pk, 2, 0, cH);
    GEMSLAB(u0pk, 3, 0, cH);
    __syncthreads();                   // all waves done reading h0_old (and xfr)
    ELEM(0, false);
    __syncthreads();                   // h0_new visible
    // ================= layer 1 =================
    CINIT(bR1, bZ1, bX1, bH1);
    GEMSLAB(w1pk, 0, 0, cN);           // input = h0_new
    GEMSLAB(w1pk, 1, 0, cN);
    GEMSLAB(w1pk, 2, 0, cN);
    GEMSLAB(w1pk, 3, 0, cN);
    GEMSLAB(u1pk, 0, 1, cH);           // hidden h1_old
    GEMSLAB(u1pk, 1, 1, cH);
    GEMSLAB(u1pk, 2, 1, cH);
    GEMSLAB(u1pk, 3, 1, cH);
    __syncthreads();                   // all waves done reading h1_old
    ELEM(1, (t == SEQT-1));
    if (t + 1 < SEQT) STAGEX(t + 1);   // stage next-t x (xfr reads done at sync#1)
    __syncthreads();                   // h1_new + xfr visible for next t
  }
  #undef CINIT
  #undef MF3
  #undef GEMSLAB
  #undef GEMSLABX
  #undef ELEM
  #undef STAGEX
}

// ===========================================================================
// GAT stage — CSR build + atomic-free per-node gather
// ===========================================================================
__global__ __launch_bounds__(256)
void gat_transform(const float* __restrict__ X, const float* __restrict__ W,
                   const float* __restrict__ asrc, const float* __restrict__ adst,
                   float* __restrict__ Hout, float* __restrict__ es, float* __restrict__ ed,
                   int n)
{
  __shared__ float sX[64*LDH];
  const int tid = threadIdx.x;
  const long base = (long)blockIdx.x * 64;
  for (int i = tid; i < 64*32; i += 256){
    int row = i >> 5, q = i & 31;
    long gr = base + row;
    float4 v = make_float4(0.f, 0.f, 0.f, 0.f);
    if (gr < n) v = ((const float4*)(X + gr*HSZ))[q];
    ((float4*)(sX + row*LDH))[q] = v;
  }
  __syncthreads();
  const int rp = tid >> 3, dg = tid & 7;
  const int r0 = rp*2, r1 = r0 + 1;
  const float4* xa = (const float4*)(sX + r0*LDH);
  const float4* xb = (const float4*)(sX + r1*LDH);
  float ps0=0.f, pd0=0.f, ps1=0.f, pd1=0.f;
  for (int dd = 0; dd < 16; ++dd){
    const int cidx = dg*16 + dd;
    const float4* wp = (const float4*)(W + cidx*HSZ);
    float a0 = 0.f, a1 = 0.f;
    #pragma unroll 4
    for (int q = 0; q < 32; ++q){
      float4 w = wp[q];
      a0 += dot4f(w, xa[q]);
      a1 += dot4f(w, xb[q]);
    }
    float s = asrc[cidx], dv = adst[cidx];
    ps0 += a0*s; pd0 += a0*dv;
    ps1 += a1*s; pd1 += a1*dv;
    if (base + r0 < n) Hout[(base+r0)*HSZ + cidx] = a0;
    if (base + r1 < n) Hout[(base+r1)*HSZ + cidx] = a1;
  }
  #pragma unroll
  for (int m = 1; m < 8; m <<= 1){
    ps0 += __shfl_xor(ps0, m, 64);
    pd0 += __shfl_xor(pd0, m, 64);
    ps1 += __shfl_xor(ps1, m, 64);
    pd1 += __shfl_xor(pd1, m, 64);
  }
  if (dg == 0){
    if (base + r0 < n){ es[base+r0] = ps0; ed[base+r0] = pd0; }
    if (base + r1 < n){ es[base+r1] = ps1; ed[base+r1] = pd1; }
  }
}

__global__ void zero_i(int* __restrict__ p, int n)
{
  int i = blockIdx.x*256 + threadIdx.x;
  if (i < n) p[i] = 0;
}

__global__ void csr_count(const int* __restrict__ key, int* __restrict__ cnt, int E)
{
  int i = blockIdx.x*256 + threadIdx.x;
  if (i < E) atomicAdd(&cnt[key[i]], 1);
}

// single block, 1024 threads: exclusive scan of cnt[0..n) -> rowptr, cursor
__global__ __launch_bounds__(1024)
void csr_scan(const int* __restrict__ cnt, int* __restrict__ rowptr,
              int* __restrict__ cursor, int n)
{
  __shared__ int ls[1024];
  const int t = threadIdx.x;
  const int base = t*20;
  int loc[20];
  int s = 0;
  #pragma unroll
  for (int k = 0; k < 20; ++k){
    int idx = base + k;
    int v = (idx < n) ? cnt[idx] : 0;
    loc[k] = s; s += v;
  }
  ls[t] = s;
  __syncthreads();
  for (int off = 1; off < 1024; off <<= 1){
    int v = (t >= off) ? ls[t-off] : 0;
    __syncthreads();
    ls[t] += v;
    __syncthreads();
  }
  int excl = (t == 0) ? 0 : ls[t-1];
  #pragma unroll
  for (int k = 0; k < 20; ++k){
    int idx = base + k;
    if (idx < n){ int rp = excl + loc[k]; rowptr[idx] = rp; cursor[idx] = rp; }
  }
  if (t == 1023) rowptr[n] = ls[1023];
}

// val==nullptr -> store the element index i (used for sector row lists)
__global__ void csr_fill(const int* __restrict__ val, const int* __restrict__ key,
                         int* __restrict__ cursor, int* __restrict__ outl, int E)
{
  int i = blockIdx.x*256 + threadIdx.x;
  if (i >= E) return;
  int p = atomicAdd(&cursor[key[i]], 1);
  outl[p] = val ? val[i] : i;
}

// one wave per destination node: leaky-relu logits, max, denom, weighted gather
__global__ __launch_bounds__(256)
void gat_gather(const int* __restrict__ rowptr, const int* __restrict__ csrc,
                const float* __restrict__ es, const float* __restrict__ ed,
                const float* __restrict__ Hv, const float* __restrict__ bias,
                float* __restrict__ out, int n)
{
  int d = blockIdx.x*4 + (threadIdx.x >> 6);
  int l = threadIdx.x & 63;
  if (d >= n) return;
  const int p0 = rowptr[d], p1 = rowptr[d+1];
  const float edd = ed[d];
  float eself = es[d] + edd;
  eself = eself > 0.f ? eself : 0.2f*eself;
  float m = eself;
  for (int j = p0 + l; j < p1; j += 64){
    int s = csrc[j];
    float e = es[s] + edd;
    e = e > 0.f ? e : 0.2f*e;
    m = fmaxf(m, e);
  }
  #pragma unroll
  for (int off = 1; off < 64; off <<= 1) m = fmaxf(m, __shfl_xor(m, off, 64));
  float part = 0.f;
  for (int j = p0 + l; j < p1; j += 64){
    int s = csrc[j];
    float e = es[s] + edd;
    e = e > 0.f ? e : 0.2f*e;
    part += __expf(e - m);
  }
  #pragma unroll
  for (int off = 1; off < 64; off <<= 1) part += __shfl_xor(part, off, 64);
  const float wself = __expf(eself - m);
  const float inv = 1.f/(part + wself);
  float a = wself*inv;
  float acc0 = a * Hv[(long)d*HSZ + l];
  float acc1 = a * Hv[(long)d*HSZ + 64 + l];
  for (int j = p0; j < p1; ++j){
    int s = csrc[j];
    float e = es[s] + edd;
    e = e > 0.f ? e : 0.2f*e;
    float al = __expf(e - m)*inv;
    acc0 += al * Hv[(long)s*HSZ + l];
    acc1 += al * Hv[(long)s*HSZ + 64 + l];
  }
  out[(long)d*HSZ + l]      = acc0 + bias[l];
  out[(long)d*HSZ + 64 + l] = acc1 + bias[64 + l];
}

// per-sector max pool using sector row-list (CSR over sid)
__global__ __launch_bounds__(256)
void sector_pool(const float* __restrict__ intra, const int* __restrict__ srowptr,
                 const int* __restrict__ slist, float* __restrict__ spool)
{
  const int sec = blockIdx.x;
  const int t = threadIdx.x;
  const int d = t & 127, half = t >> 7;
  const int p0 = srowptr[sec], p1 = srowptr[sec+1];
  float m = -3.402823466e+38f;
  for (int j = p0 + half; j < p1; j += 2){
    int r = slist[j];
    m = fmaxf(m, intra[(long)r*HSZ + d]);
  }
  __shared__ float red[256];
  red[t] = m;
  __syncthreads();
  if (half == 0) spool[sec*HSZ + d] = fmaxf(red[d], red[128 + d]);
}

// ---- inter-sector GAT (tiny, keep atomic path) ----
__global__ void gat_init(unsigned* __restrict__ maxb, float* __restrict__ den,
                         float* __restrict__ acc, int n)
{
  long i = (long)blockIdx.x*256 + threadIdx.x;
  if (i < n){ maxb[i] = NEG_MAX_ORD; den[i] = 0.f; }
  if (i < (long)n*HSZ) acc[i] = 0.f;
}

__global__ void edge_max(const int* __restrict__ src, const int* __restrict__ dst,
                         const float* __restrict__ es, const float* __restrict__ ed,
                         unsigned* __restrict__ maxb, int E, int n)
{
  int i = blockIdx.x*256 + threadIdx.x;
  if (i >= E + n) return;
  int s, d;
  if (i < E){ s = src[i]; d = dst[i]; } else { s = d = i - E; }
  float e = es[s] + ed[d];
  e = e > 0.f ? e : 0.2f*e;
  atomicMax(maxb + d, fordu(e));
}

__global__ void edge_sum(const int* __restrict__ src, const int* __restrict__ dst,
                         const float* __restrict__ es, const float* __restrict__ ed,
                         const unsigned* __restrict__ maxb, float* __restrict__ den,
                         float* __restrict__ wbuf, int E, int n)
{
  int i = blockIdx.x*256 + threadIdx.x;
  if (i >= E + n) return;
  int s, d;
  if (i < E){ s = src[i]; d = dst[i]; } else { s = d = i - E; }
  float e = es[s] + ed[d];
  e = e > 0.f ? e : 0.2f*e;
  float w = __expf(e - unfordu(maxb[d]));
  wbuf[i] = w;
  atomicAdd(den + d, w);
}

__global__ void edge_scatter(const int* __restrict__ src, const int* __restrict__ dst,
                             const float* __restrict__ wbuf, const float* __restrict__ den,
                             const float* __restrict__ Hv, float* __restrict__ acc,
                             int E, int n)
{
  long t = (long)blockIdx.x*256 + threadIdx.x;
  long i = t >> 5;
  int  j = (int)(t & 31);
  if (i >= E + n) return;
  int s, d;
  if (i < E){ s = src[i]; d = dst[i]; } else { s = d = (int)(i - E); }
  float alpha = wbuf[i] / den[d];
  float4 hv = ((const float4*)(Hv + (long)s*HSZ))[j];
  float* o = acc + (long)d*HSZ + j*4;
  atomicAdd(o+0, alpha*hv.x);
  atomicAdd(o+1, alpha*hv.y);
  atomicAdd(o+2, alpha*hv.z);
  atomicAdd(o+3, alpha*hv.w);
}

__global__ void inter_bias_k(const float* __restrict__ acc2, const float* __restrict__ bias,
                             float* __restrict__ isec)
{
  int i = blockIdx.x*256 + threadIdx.x;   // exactly 64*128
  isec[i] = acc2[i] + bias[i & 127];
}

__global__ __launch_bounds__(256)
void fusion_k(const float* __restrict__ seq, const float* __restrict__ intra,
              const float* __restrict__ isec, const int* __restrict__ sid,
              const float* __restrict__ fw, const float* __restrict__ fb,
              float* __restrict__ out, int n)
{
  int i = blockIdx.x*4 + (threadIdx.x >> 6);
  int l = threadIdx.x & 63;
  if (i >= n) return;
  int sc = sid[i];
  long b = (long)i*HSZ;
  long sb = (long)sc*HSZ;
  float acc = fw[l]     * seq[b + l]      + fw[64 + l]  * seq[b + 64 + l]
            + fw[128+l] * intra[b + l]    + fw[192 + l] * intra[b + 64 + l]
            + fw[256+l] * isec[sb + l]    + fw[320 + l] * isec[sb + 64 + l];
  #pragma unroll
  for (int m = 1; m < 64; m <<= 1) acc += __shfl_xor(acc, m, 64);
  if (l == 0) out[i] = acc + fb[0];
}

extern "C" void kernel_launch(void* const* d_in, const int* in_sizes, int n_in,
                              void* d_out, int out_size, void* d_ws, size_t ws_size,
                              hipStream_t stream)
{
  const float* x    = (const float*)d_in[0];
  const int*   iei  = (const int*)d_in[1];    // [2, 640000]
  const int*   eei  = (const int*)d_in[2];    // [2, 4096]
  const int*   sid  = (const int*)d_in[3];
  const float* wih0 = (const float*)d_in[4];
  const float* whh0 = (const float*)d_in[5];
  const float* bih0 = (const float*)d_in[6];
  const float* bhh0 = (const float*)d_in[7];
  const float* wih1 = (const float*)d_in[8];
  const float* whh1 = (const float*)d_in[9];
  const float* bih1 = (const float*)d_in[10];
  const float* bhh1 = (const float*)d_in[11];
  const float* iW   = (const float*)d_in[12];
  const float* ias  = (const float*)d_in[13];
  const float* iad  = (const float*)d_in[14];
  const float* ib   = (const float*)d_in[15];
  const float* eW   = (const float*)d_in[16];
  const float* eas  = (const float*)d_in[17];
  const float* ead  = (const float*)d_in[18];
  const float* eb   = (const float*)d_in[19];
  const float* fW   = (const float*)d_in[20];
  const float* fb   = (const float*)d_in[21];

  float* ws = (float*)d_ws;
  long off = 0;
  float* seq    = ws + off; off += 2560000;
  float* hintra = ws + off; off += 2560000;
  float* intra  = ws + off; off += 2560000;
  float* es     = ws + off; off += 20000;
  float* ed     = ws + off; off += 20000;
  int*   cnt    = (int*)(ws + off); off += 20000;
  int*   rowptr = (int*)(ws + off); off += 20004;
  int*   cursor = (int*)(ws + off); off += 20000;
  int*   csrc   = (int*)(ws + off); off += 640000;
  int*   scnt    = (int*)(ws + off); off += 64;
  int*   srowptr = (int*)(ws + off); off += 68;
  int*   scursor = (int*)(ws + off); off += 64;
  int*   slist   = (int*)(ws + off); off += 20000;
  float* w0p = ws + off; off += 24576;   // bf16x3 pack: 2kt*24nt*2*1024B
  float* u0p = ws + off; off += 49152;   // 4kt
  float* w1p = ws + off; off += 49152;
  float* u1p = ws + off; off += 49152;
  float* spool  = ws + off; off += 8192;
  float* hinter = ws + off; off += 8192;
  float* acc2   = ws + off; off += 8192;
  float* es2    = ws + off; off += 64;
  float* ed2    = ws + off; off += 64;
  unsigned* mx2 = (unsigned*)(ws + off); off += 64;
  float* den2   = ws + off; off += 64;
  float* wbf2   = ws + off; off += 4160;
  float* isec   = ws + off; off += 8192;
  // total ~8.6M floats = ~34.5 MB

  // 0) pack GRU weights into bf16 hi/lo MFMA fragment layout
  wpack_mfma<<<12, 256, 0, stream>>>(wih0, (unsigned short*)w0p, 64);
  wpack_mfma<<<24, 256, 0, stream>>>(whh0, (unsigned short*)u0p, 128);
  wpack_mfma<<<24, 256, 0, stream>>>(wih1, (unsigned short*)w1p, 128);
  wpack_mfma<<<24, 256, 0, stream>>>(whh1, (unsigned short*)u1p, 128);

  // 1) MFMA bf16x3 fused 2-layer GRU -> seq_emb (250 blocks x 512 thr, M=80)
  gru_mfma<<<250, 512, 0, stream>>>(x,
                                    (const unsigned short*)w0p, (const unsigned short*)u0p,
                                    (const unsigned short*)w1p, (const unsigned short*)u1p,
                                    bih0, bhh0, bih1, bhh1, seq);

  // 2) intra GAT: transform + CSR build + atomic-free gather
  gat_transform<<<313, 256, 0, stream>>>(seq, iW, ias, iad, hintra, es, ed, NCOMP);
  zero_i   <<<(NCOMP+255)/256, 256, 0, stream>>>(cnt, NCOMP);
  zero_i   <<<1, 256, 0, stream>>>(scnt, NSEC);
  csr_count<<<(EINTRA+255)/256, 256, 0, stream>>>(iei + EINTRA, cnt, EINTRA);
  csr_count<<<(NCOMP+255)/256, 256, 0, stream>>>(sid, scnt, NCOMP);
  csr_scan <<<1, 1024, 0, stream>>>(cnt, rowptr, cursor, NCOMP);
  csr_scan <<<1, 1024, 0, stream>>>(scnt, srowptr, scursor, NSEC);
  csr_fill <<<(EINTRA+255)/256, 256, 0, stream>>>(iei, iei + EINTRA, cursor, csrc, EINTRA);
  csr_fill <<<(NCOMP+255)/256, 256, 0, stream>>>(nullptr, sid, scursor, slist, NCOMP);
  gat_gather<<<NCOMP/4, 256, 0, stream>>>(rowptr, csrc, es, ed, hintra, ib, intra, NCOMP);

  // 3) per-sector max pool via sector row lists
  sector_pool<<<NSEC, 256, 0, stream>>>(intra, srowptr, slist, spool);

  // 4) inter GAT (tiny: 64 nodes, 4096 edges — atomic path)
  gat_init<<<32, 256, 0, stream>>>(mx2, den2, acc2, NSEC);
  gat_transform<<<1, 256, 0, stream>>>(spool, eW, eas, ead, hinter, es2, ed2, NSEC);
  {
    int tot = EINTER + NSEC;
    edge_max    <<<(tot+255)/256, 256, 0, stream>>>(eei, eei+EINTER, es2, ed2, mx2, EINTER, NSEC);
    edge_sum    <<<(tot+255)/256, 256, 0, stream>>>(eei, eei+EINTER, es2, ed2, mx2, den2, wbf2, EINTER, NSEC);
    edge_scatter<<<(tot*32)/256, 256, 0, stream>>>(eei, eei+EINTER, wbf2, den2, hinter, acc2, EINTER, NSEC);
  }
  inter_bias_k<<<32, 256, 0, stream>>>(acc2, eb, isec);

  // 5) fusion -> output [20000]
  fusion_k<<<NCOMP/4, 256, 0, stream>>>(seq, intra, isec, sid, fW, fb, (float*)d_out, NCOMP);
}